// Round 3
// baseline (566.541 us; speedup 1.0000x reference)
//
#include <hip/hip_runtime.h>

#define NN 40000
#define EE 640000
#define DD 128
#define LL 5
#define NB 157          // buckets of 256 dst nodes
#define CAP 8192        // slots per bucket (mean ~4076, sigma ~64)
#define NB2 500         // k_g2f blocks: 80 rows each, all co-resident (<=1024)

typedef unsigned short u16;
typedef unsigned int   u32;
typedef __attribute__((ext_vector_type(8))) short bf8;   // 8 bf16 = 4 VGPRs
typedef __attribute__((ext_vector_type(4))) float f4;

__device__ __forceinline__ float bf2f(u32 u){ union{u32 i; float f;} x; x.i = u << 16; return x.f; }
__device__ __forceinline__ u16 f2bf(float f){
  union{float f; u32 i;} x; x.f = f;
  u32 r = x.i + 0x7FFFu + ((x.i >> 16) & 1u);
  return (u16)(r >> 16);
}
__device__ __forceinline__ u32 pack2(float a, float b){ return (u32)f2bf(a) | ((u32)f2bf(b) << 16); }

// col packing: src[0:16] | attr<<17 | xid<<19   (sentinel: src=NN, xid=31)

// ---- device-wide barrier (only used by k_g2f: 500 blocks, all co-resident) ----
__device__ __forceinline__ void gridbar(int* cnt, int* gen){
  __syncthreads();
  if (threadIdx.x == 0){
    __threadfence();
    int g = __hip_atomic_load(gen, __ATOMIC_RELAXED, __HIP_MEMORY_SCOPE_AGENT);
    if (__hip_atomic_fetch_add(cnt, 1, __ATOMIC_RELAXED, __HIP_MEMORY_SCOPE_AGENT) == NB2 - 1){
      __hip_atomic_store(cnt, 0, __ATOMIC_RELAXED, __HIP_MEMORY_SCOPE_AGENT);
      __threadfence();
      __hip_atomic_fetch_add(gen, 1, __ATOMIC_RELEASE, __HIP_MEMORY_SCOPE_AGENT);
    } else {
      while (__hip_atomic_load(gen, __ATOMIC_RELAXED, __HIP_MEMORY_SCOPE_AGENT) == g)
        __builtin_amdgcn_s_sleep(2);
    }
    __threadfence();
  }
  __syncthreads();
}

// ---------------- prologue A: init h/deg/gcur/bar + hb sentinel | wprep ----------------
__global__ void k_pre(const int* __restrict__ x_ids, const float* __restrict__ atom_emb,
                      float* __restrict__ h, u32* __restrict__ hb, int* __restrict__ deg,
                      const float* __restrict__ W1, const float* __restrict__ W2,
                      u16* __restrict__ wt, int* __restrict__ gcur, int* __restrict__ bar){
  int bid = blockIdx.x, tid = threadIdx.x;
  if (bid < 5000){                                // init: NN*32 items (4 feats/thread)
    int idx = bid * 256 + tid;
    if (idx < NN) deg[idx] = 0;
    if (idx < 160) gcur[idx] = 0;
    if (idx < 64) bar[idx] = 0;
    if (idx < 32){ uint2 s; s.x = 0xFF80FF80u; s.y = 0xFF80FF80u;  // dummy node row: -inf
      ((uint2*)(hb + NN * 64))[idx] = s; }
    int n = idx >> 5, d4 = idx & 31;
    float4 v = ((const float4*)(atom_emb + x_ids[n] * DD))[d4];
    ((float4*)h)[idx] = v;
  } else {                                        // wprep: 10*16384 items
    int idx = (bid - 5000) * 256 + tid;
    int m = idx >> 14, nk = idx & 16383;
    int n = nk >> 7, k = nk & 127;
    const float* src = (m < LL) ? (W1 + m * 16384) : (W2 + (m - LL) * 16384);
    wt[idx] = f2bf(src[k * DD + n]);
  }
}

// ---------------- prologue B: count degrees + bucket edges ----------------
__global__ __launch_bounds__(1024) void k_bin(const int* __restrict__ ei, const int* __restrict__ ea,
                                              int* __restrict__ deg, int* __restrict__ gcur,
                                              u32* __restrict__ store){
  __shared__ int l_cnt[160];
  __shared__ int l_base[160];
  int tid = threadIdx.x;
  if (tid < 160) l_cnt[tid] = 0;
  __syncthreads();
  int e0 = blockIdx.x * 4096;                     // 157 x 4096 >= EE
  u32 rec[4]; int rb[4], rr[4];
  #pragma unroll
  for (int j = 0; j < 4; ++j){
    int e = e0 + j * 1024 + tid;
    rb[j] = -1;
    if (e < EE){
      int dst = ei[EE + e];
      atomicAdd(&deg[dst], 1);
      int b = dst >> 8;
      rb[j] = b;
      rr[j] = atomicAdd(&l_cnt[b], 1);
      rec[j] = (u32)ei[e] | ((u32)ea[e] << 16) | ((u32)(dst & 255) << 18);
    }
  }
  __syncthreads();
  if (tid < 160) l_base[tid] = atomicAdd(&gcur[tid], l_cnt[tid]);
  __syncthreads();
  #pragma unroll
  for (int j = 0; j < 4; ++j)
    if (rb[j] >= 0)
      store[rb[j] * CAP + l_base[rb[j]] + rr[j]] = rec[j];
}

// phase 1: per-block exclusive scan of degrees PADDED TO x8 + block totals (40 blocks x 1024)
__global__ void k_scan1(const int* __restrict__ deg, int* __restrict__ rs, int* __restrict__ bsum){
  __shared__ int buf[1024];
  int tid = threadIdx.x;
  int i = blockIdx.x * 1024 + tid;
  int dv = (i < NN) ? deg[i] : 0;
  int v = (dv + 7) & ~7;                         // pad each segment to x8 (16-wide gather groups)
  buf[tid] = v;
  __syncthreads();
  for (int off = 1; off < 1024; off <<= 1){
    int t = (tid >= off) ? buf[tid - off] : 0;
    __syncthreads();
    buf[tid] += t;
    __syncthreads();
  }
  int incl = buf[tid];
  if (i < NN) rs[i] = incl - v;                  // chunk-local exclusive
  if (tid == 1023) bsum[blockIdx.x] = incl;
}

// ---------------- place2: scan2-inline + scatter (with xid packing) + sentinel + stats1 zero ----------------
__global__ __launch_bounds__(1024) void k_place2(const u32* __restrict__ store, const int* __restrict__ gcur,
                                                 const int* __restrict__ rs, int* __restrict__ rs2,
                                                 int* __restrict__ col, const int* __restrict__ bsum,
                                                 float* __restrict__ stats1, const int* __restrict__ x_ids){
  __shared__ int l_cur[256];
  __shared__ int s_choff[41];
  int b = blockIdx.x, tid = threadIdx.x;
  if (b == 0){ stats1[tid] = 0.f; stats1[1024 + tid] = 0.f; }
  if (tid < 64){
    int v = (tid < 40) ? bsum[tid] : 0;
    #pragma unroll
    for (int off = 1; off < 64; off <<= 1){
      int t = __shfl_up(v, off, 64);
      if (tid >= off) v += t;
    }
    if (tid < 40){
      s_choff[tid] = v - bsum[tid];              // exclusive chunk offset
      if (tid == 39) s_choff[40] = v;            // padded total
    }
  }
  __syncthreads();
  int n0 = b << 8;
  if (tid < 256){
    int n = n0 + tid;
    if (n < NN){
      int g = rs[n] + s_choff[n >> 10];
      l_cur[tid] = g;
      rs2[n] = g;
    }
  }
  if (b == NB - 1 && tid == 0) rs2[NN] = s_choff[40];
  __syncthreads();
  int cnt = gcur[b];
  for (int r = tid; r < cnt; r += 1024){
    u32 rec = store[b * CAP + r];
    int dl = rec >> 18;
    int src = (int)(rec & 0xFFFFu);
    int attr = (int)((rec >> 16) & 3u);
    int xid = x_ids[src];                        // 0..27, L2-resident table
    int pos = atomicAdd(&l_cur[dl], 1);
    col[pos] = src | (attr << 17) | (xid << 19);
  }
  __syncthreads();
  if (tid < 256){                                 // pad gaps with sentinel (dummy node NN, xid 31)
    int n = n0 + tid;
    if (n < NN){
      int e = l_cur[tid];
      int end = (n + 1 < NN) ? (rs[n + 1] + s_choff[(n + 1) >> 10]) : s_choff[40];
      for (; e < end; ++e) col[e] = NN | (31 << 19);
    }
  }
}

// ---------------- FUSED gather + GEMM1 (round-0 proven shape: 32 rows, 16-outstanding) ----------------
// L0: gather sources come from the 32-row LDS atom table (rows 28..31 = -inf) instead of hb.
template<bool L0>
__global__ __launch_bounds__(256, 4) void k_gg(
    const float* __restrict__ h, const u32* __restrict__ hb,
    const int* __restrict__ row_start, const int* __restrict__ col,
    const float* __restrict__ bond_l, const float* __restrict__ eps_l,
    const u16* __restrict__ Wt, const float* __restrict__ bias,
    u16* __restrict__ out, float* __restrict__ osum, float* __restrict__ stats2,
    const float* __restrict__ atom_emb){
  __shared__ u16 sA[32 * 136];
  __shared__ float2 s_bond[4 * 64];
  __shared__ float s_eps;
  __shared__ float s_sum[DD], s_sq[DD];
  __shared__ u32 s_atom[L0 ? 32 * 64 : 64];       // L0 only: 32 rows x 128 bf16
  int tid = threadIdx.x;
  if (blockIdx.x == 0){                           // zero stats2 for this layer
    #pragma unroll
    for (int j = 0; j < 8; ++j) stats2[j * 256 + tid] = 0.f;
  }
  if (tid < 256) s_bond[tid] = ((const float2*)bond_l)[tid];
  if (tid == 0) s_eps = 1.0f + eps_l[0];
  if (tid < DD){ s_sum[tid] = 0.f; s_sq[tid] = 0.f; }
  if (L0){
    #pragma unroll
    for (int j = 0; j < 8; ++j){
      int idx = j * 256 + tid;                    // row = idx>>6, pair = idx&63
      int row = idx >> 6, pr = idx & 63;
      u32 v = 0xFF80FF80u;
      if (row < 28){
        float2 ae = ((const float2*)(atom_emb + row * DD))[pr];
        v = pack2(ae.x, ae.y);
      }
      s_atom[idx] = v;
    }
  }
  __syncthreads();
  int w = tid >> 6, lane = tid & 63;
  int vbase = blockIdx.x * 32 + w * 8;
  int sprev = __builtin_amdgcn_readfirstlane(row_start[vbase]);
  for (int j = 0; j < 8; ++j){
    int v = vbase + j;
    int send = __builtin_amdgcn_readfirstlane(row_start[v + 1]);  // multiple of 8
    int i = sprev; sprev = send;
    float accx[4] = {0.f, 0.f, 0.f, 0.f};
    float accy[4] = {0.f, 0.f, 0.f, 0.f};
    for (; i + 16 <= send; i += 16){              // 16 outstanding loads
      int4 c0 = *(const int4*)(col + i);
      int4 c1 = *(const int4*)(col + i + 4);
      int4 c2 = *(const int4*)(col + i + 8);
      int4 c3 = *(const int4*)(col + i + 12);
      int id[16] = {c0.x, c0.y, c0.z, c0.w, c1.x, c1.y, c1.z, c1.w,
                    c2.x, c2.y, c2.z, c2.w, c3.x, c3.y, c3.z, c3.w};
      u32 hx[16];
      #pragma unroll
      for (int q = 0; q < 16; ++q)
        hx[q] = L0 ? s_atom[((id[q] >> 19) & 31) * 64 + lane]
                   : hb[(id[q] & 0x1FFFF) * 64 + lane];
      #pragma unroll
      for (int q = 0; q < 16; ++q){
        float2 bb = s_bond[((id[q] >> 17) & 3) * 64 + lane];
        accx[q & 3] += fmaxf(bf2f(hx[q] & 0xFFFFu) + bb.x, 0.f);
        accy[q & 3] += fmaxf(bf2f(hx[q] >> 16)     + bb.y, 0.f);
      }
    }
    if (i < send){                                // exactly one 8-group remains
      int4 c0 = *(const int4*)(col + i);
      int4 c1 = *(const int4*)(col + i + 4);
      int id[8] = {c0.x, c0.y, c0.z, c0.w, c1.x, c1.y, c1.z, c1.w};
      u32 hx[8];
      #pragma unroll
      for (int q = 0; q < 8; ++q)
        hx[q] = L0 ? s_atom[((id[q] >> 19) & 31) * 64 + lane]
                   : hb[(id[q] & 0x1FFFF) * 64 + lane];
      #pragma unroll
      for (int q = 0; q < 8; ++q){
        float2 bb = s_bond[((id[q] >> 17) & 3) * 64 + lane];
        accx[q & 3] += fmaxf(bf2f(hx[q] & 0xFFFFu) + bb.x, 0.f);
        accy[q & 3] += fmaxf(bf2f(hx[q] >> 16)     + bb.y, 0.f);
      }
    }
    float2 hv = ((const float2*)h)[v * 64 + lane];
    u32 zp = pack2(s_eps * hv.x + (accx[0] + accx[1]) + (accx[2] + accx[3]),
                   s_eps * hv.y + (accy[0] + accy[1]) + (accy[2] + accy[3]));
    *(u32*)(sA + (w * 8 + j) * 136 + lane * 2) = zp;
  }
  int lr = lane & 15, lk = lane >> 4;
  bf8 bfr[2][4];
  #pragma unroll
  for (int nt = 0; nt < 2; ++nt){
    int n = w * 32 + nt * 16 + lr;
    #pragma unroll
    for (int kt = 0; kt < 4; ++kt)
      bfr[nt][kt] = *(const bf8*)(Wt + n * DD + kt * 32 + lk * 8);
  }
  __syncthreads();
  f4 acc[2][2];
  #pragma unroll
  for (int mt = 0; mt < 2; ++mt)
    #pragma unroll
    for (int nt = 0; nt < 2; ++nt) acc[mt][nt] = (f4){0.f, 0.f, 0.f, 0.f};
  #pragma unroll
  for (int kt = 0; kt < 4; ++kt){
    bf8 a0 = *(const bf8*)(sA + lr * 136        + kt * 32 + lk * 8);
    bf8 a1 = *(const bf8*)(sA + (16 + lr) * 136 + kt * 32 + lk * 8);
    acc[0][0] = __builtin_amdgcn_mfma_f32_16x16x32_bf16(a0, bfr[0][kt], acc[0][0], 0, 0, 0);
    acc[0][1] = __builtin_amdgcn_mfma_f32_16x16x32_bf16(a0, bfr[1][kt], acc[0][1], 0, 0, 0);
    acc[1][0] = __builtin_amdgcn_mfma_f32_16x16x32_bf16(a1, bfr[0][kt], acc[1][0], 0, 0, 0);
    acc[1][1] = __builtin_amdgcn_mfma_f32_16x16x32_bf16(a1, bfr[1][kt], acc[1][1], 0, 0, 0);
  }
  int row0 = blockIdx.x * 32;
  #pragma unroll
  for (int nt = 0; nt < 2; ++nt){
    int colg = w * 32 + nt * 16 + lr;
    float bv = bias[colg];
    float cs = 0.f, cq = 0.f;
    #pragma unroll
    for (int mt = 0; mt < 2; ++mt){
      #pragma unroll
      for (int r = 0; r < 4; ++r){
        u16 yb = f2bf(acc[mt][nt][r] + bv);
        float yr = bf2f(yb);
        out[(row0 + mt * 16 + lk * 4 + r) * DD + colg] = yb;
        cs += yr; cq += yr * yr;
      }
    }
    atomicAdd(&s_sum[colg], cs);
    atomicAdd(&s_sq[colg], cq);
  }
  __syncthreads();
  float* slice = osum + (blockIdx.x & 7) * 256;
  if (tid < DD){
    atomicAdd(&slice[tid],      s_sum[tid]);
    atomicAdd(&slice[DD + tid], s_sq[tid]);
  }
}

// ---------------- FUSED GEMM2 + BN2 + residual (one internal grid barrier) ----------------
// 500 blocks x 80 rows, all co-resident (500 <= 256CU x 4blk). z2 never leaves LDS.
__global__ __launch_bounds__(256, 4) void k_g2f(
    const u16* __restrict__ Asrc,              // z2b (gemm1 out, bf16)
    const u16* __restrict__ Wt, const float* __restrict__ bias,   // W2^T, b2
    const float* __restrict__ stats1,          // in: 8 slices [sum128|sq128]
    const float* __restrict__ g, const float* __restrict__ bt,    // g1, bt1
    float* __restrict__ stats2,                // out: 8 slices (pre-zeroed by k_gg)
    const float* __restrict__ gl, const float* __restrict__ bl,   // g_out, b_out
    float* __restrict__ h, u32* __restrict__ hb, int do_relu,
    float* __restrict__ stats1z, int* __restrict__ bar){
  __shared__ u16 sA[80 * 136];                   // BN1'd A, then overwritten with z2 bf16
  __shared__ float s_scale[DD], s_shift[DD];
  __shared__ float s_sum[DD], s_sq[DD];
  int tid = threadIdx.x;
  int row0 = blockIdx.x * 80;
  // ---- BN1 coefficients from stats1 ----
  if (tid < DD){
    s_sum[tid] = 0.f; s_sq[tid] = 0.f;
    float s = 0.f, q = 0.f;
    #pragma unroll
    for (int s8 = 0; s8 < 8; ++s8){
      s += stats1[s8 * 256 + tid];
      q += stats1[s8 * 256 + DD + tid];
    }
    float m   = s * (1.0f / NN);
    float var = q * (1.0f / NN) - m * m;
    float inv = rsqrtf(var + 1e-5f);
    float sc  = inv * g[tid];
    s_scale[tid] = sc;
    s_shift[tid] = bt[tid] - m * sc;
  }
  __syncthreads();
  // ---- stage 80 rows: BN1 + ReLU -> sA (bf16) ----
  #pragma unroll
  for (int c0 = 0; c0 < 5; ++c0){
    int c = tid + c0 * 256;
    int row = c >> 4, off = (c & 15) * 8;
    uint4 v = *(const uint4*)(Asrc + (row0 + row) * DD + off);
    u32 wv[4] = {v.x, v.y, v.z, v.w};
    union { u16 o[8]; uint4 v; } u;
    #pragma unroll
    for (int j = 0; j < 4; ++j){
      float y0 = bf2f(wv[j] & 0xFFFFu) * s_scale[off + 2*j]     + s_shift[off + 2*j];
      float y1 = bf2f(wv[j] >> 16)     * s_scale[off + 2*j + 1] + s_shift[off + 2*j + 1];
      u.o[2*j]     = f2bf(fmaxf(y0, 0.f));
      u.o[2*j + 1] = f2bf(fmaxf(y1, 0.f));
    }
    *(uint4*)(sA + row * 136 + off) = u.v;
  }
  int w = tid >> 6, lane = tid & 63, lr = lane & 15, lk = lane >> 4;
  bf8 bfr[2][4];
  #pragma unroll
  for (int nt = 0; nt < 2; ++nt){
    int n = w * 32 + nt * 16 + lr;
    #pragma unroll
    for (int kt = 0; kt < 4; ++kt)
      bfr[nt][kt] = *(const bf8*)(Wt + n * DD + kt * 32 + lk * 8);
  }
  __syncthreads();
  f4 acc[5][2];
  #pragma unroll
  for (int mt = 0; mt < 5; ++mt){ acc[mt][0] = (f4){0.f,0.f,0.f,0.f}; acc[mt][1] = (f4){0.f,0.f,0.f,0.f}; }
  #pragma unroll
  for (int kt = 0; kt < 4; ++kt){
    #pragma unroll
    for (int mt = 0; mt < 5; ++mt){
      bf8 a = *(const bf8*)(sA + (mt * 16 + lr) * 136 + kt * 32 + lk * 8);
      acc[mt][0] = __builtin_amdgcn_mfma_f32_16x16x32_bf16(a, bfr[0][kt], acc[mt][0], 0, 0, 0);
      acc[mt][1] = __builtin_amdgcn_mfma_f32_16x16x32_bf16(a, bfr[1][kt], acc[mt][1], 0, 0, 0);
    }
  }
  __syncthreads();                                // all sA reads done -> safe to overwrite
  // ---- epilogue: +b2, bf16 -> sA, stats2 ----
  #pragma unroll
  for (int nt = 0; nt < 2; ++nt){
    int colg = w * 32 + nt * 16 + lr;
    float bv = bias[colg];
    float cs = 0.f, cq = 0.f;
    #pragma unroll
    for (int mt = 0; mt < 5; ++mt){
      #pragma unroll
      for (int r = 0; r < 4; ++r){
        u16 yb = f2bf(acc[mt][nt][r] + bv);
        float yr = bf2f(yb);
        sA[(mt * 16 + lk * 4 + r) * 136 + colg] = yb;
        cs += yr; cq += yr * yr;
      }
    }
    atomicAdd(&s_sum[colg], cs);
    atomicAdd(&s_sq[colg], cq);
  }
  __syncthreads();
  if (tid < DD){
    atomicAdd(&stats2[(blockIdx.x & 7) * 256 + tid],      s_sum[tid]);
    atomicAdd(&stats2[(blockIdx.x & 7) * 256 + DD + tid], s_sq[tid]);
  }
  gridbar(bar, bar + 1);                          // stats2 complete everywhere
  // ---- BN2 coefficients + zero stats1 for next layer ----
  if (tid < DD){
    float s = 0.f, q = 0.f;
    #pragma unroll
    for (int s8 = 0; s8 < 8; ++s8){
      s += stats2[s8 * 256 + tid];
      q += stats2[s8 * 256 + DD + tid];
    }
    float m   = s * (1.0f / NN);
    float var = q * (1.0f / NN) - m * m;
    float inv = rsqrtf(var + 1e-5f);
    float sc  = inv * gl[tid];
    s_scale[tid] = sc;
    s_shift[tid] = bl[tid] - m * sc;
  }
  if (blockIdx.x == 0){
    #pragma unroll
    for (int j = 0; j < 8; ++j) stats1z[j * 256 + tid] = 0.f;
  }
  __syncthreads();
  // ---- BN2 (+ReLU except last) + residual; h fp32 + hb bf16 (skip hb on last) ----
  #pragma unroll
  for (int c0 = 0; c0 < 5; ++c0){
    int idx = tid + c0 * 256;                     // 80*16 chunks of 8 feats
    int row = idx >> 4, off8 = (idx & 15) * 8;
    uint4 zz = *(const uint4*)(sA + row * 136 + off8);
    u32 zw[4] = {zz.x, zz.y, zz.z, zz.w};
    float4* hp = (float4*)(h + (row0 + row) * DD + off8);
    float4 hv0 = hp[0], hv1 = hp[1];
    float vv[8];
    #pragma unroll
    for (int j2 = 0; j2 < 4; ++j2){
      float y0 = bf2f(zw[j2] & 0xFFFFu) * s_scale[off8 + 2*j2]     + s_shift[off8 + 2*j2];
      float y1 = bf2f(zw[j2] >> 16)     * s_scale[off8 + 2*j2 + 1] + s_shift[off8 + 2*j2 + 1];
      if (do_relu){ y0 = fmaxf(y0, 0.f); y1 = fmaxf(y1, 0.f); }
      vv[2*j2] = y0; vv[2*j2 + 1] = y1;
    }
    hv0.x += vv[0]; hv0.y += vv[1]; hv0.z += vv[2]; hv0.w += vv[3];
    hv1.x += vv[4]; hv1.y += vv[5]; hv1.z += vv[6]; hv1.w += vv[7];
    hp[0] = hv0; hp[1] = hv1;
    if (do_relu){                                 // last layer: hb is dead, skip
      uint4 pk;
      pk.x = pack2(hv0.x, hv0.y); pk.y = pack2(hv0.z, hv0.w);
      pk.z = pack2(hv1.x, hv1.y); pk.w = pack2(hv1.z, hv1.w);
      *(uint4*)(hb + (row0 + row) * 64 + (idx & 15) * 4) = pk;
    }
  }
}

extern "C" void kernel_launch(void* const* d_in, const int* in_sizes, int n_in,
                              void* d_out, int out_size, void* d_ws, size_t ws_size,
                              hipStream_t stream) {
  const int*   x_ids      = (const int*)d_in[0];
  const int*   edge_index = (const int*)d_in[1];
  const int*   edge_attr  = (const int*)d_in[2];
  const float* atom_emb   = (const float*)d_in[3];
  const float* bond_emb   = (const float*)d_in[4];
  const float* W1    = (const float*)d_in[5];
  const float* b1    = (const float*)d_in[6];
  const float* g1    = (const float*)d_in[7];
  const float* bt1   = (const float*)d_in[8];
  const float* W2    = (const float*)d_in[9];
  const float* b2    = (const float*)d_in[10];
  const float* eps   = (const float*)d_in[11];
  const float* g_out = (const float*)d_in[12];
  const float* b_out = (const float*)d_in[13];

  float* h   = (float*)d_out;                 // NN*DD fp32 running node state
  u32*   zb  = (u32*)d_ws;                    // prologue: bin store; loop: unused
  u32*   z2b = zb  + NN * 64;                 // NN*64: bf16 gemm1 out
  u32*   hb  = z2b + NN * 64;                 // (NN+1)*64: bf16 mirror of h + sentinel row
  u16*   wt  = (u16*)(hb + (NN + 1) * 64);    // 10*16384 bf16 transposed weights
  float* stats = (float*)(wt + 10 * 16384);   // 4096: stats1[0..2047] | stats2[2048..4095]
  int* bar       = (int*)(stats + 4096);      // [0]=count [1]=gen (+pad)
  int* rs        = bar + 64;                  // NN+4 (chunk-local scan)
  int* rs2       = rs + NN + 4;               // NN+4 (finalized row offsets)
  int* deg       = rs2 + NN + 4;
  int* col       = deg + NN;                  // EE + 7*NN (x8-padded)
  int* bsum      = col + EE + 7 * NN;         // 40
  int* gcur      = bsum + 64;                 // 160 bucket cursors

  u32* store = zb;                            // NB*CAP u32 records (5.1 MB; dead before loop)

  k_pre   <<<5640, 256, 0, stream>>>(x_ids, atom_emb, h, hb, deg, W1, W2, wt, gcur, bar);
  k_bin   <<<NB, 1024, 0, stream>>>(edge_index, edge_attr, deg, gcur, store);
  k_scan1 <<<40, 1024, 0, stream>>>(deg, rs, bsum);
  k_place2<<<NB, 1024, 0, stream>>>(store, gcur, rs, rs2, col, bsum, stats, x_ids);

  for (int l = 0; l < LL; ++l){
    if (l == 0)
      k_gg<true> <<<NN / 32, 256, 0, stream>>>(h, hb, rs2, col,
                                               bond_emb + l * 4 * DD, eps + l,
                                               wt + l * 16384, b1 + l * DD,
                                               (u16*)z2b, stats, stats + 2048, atom_emb);
    else
      k_gg<false><<<NN / 32, 256, 0, stream>>>(h, hb, rs2, col,
                                               bond_emb + l * 4 * DD, eps + l,
                                               wt + l * 16384, b1 + l * DD,
                                               (u16*)z2b, stats, stats + 2048, atom_emb);
    k_g2f<<<NB2, 256, 0, stream>>>((const u16*)z2b, wt + (LL + l) * 16384, b2 + l * DD,
                                   stats, g1 + l * DD, bt1 + l * DD,
                                   stats + 2048, g_out + l * DD, b_out + l * DD,
                                   h, hb, (l < LL - 1) ? 1 : 0, stats, bar);
  }
}

// Round 5
// 468.283 us; speedup vs baseline: 1.2098x; 1.2098x over previous
//
#include <hip/hip_runtime.h>

#define NN 40000
#define EE 640000
#define DD 128
#define LL 5
#define NB 157          // buckets of 256 dst nodes
#define CAP 8192        // slots per bucket (mean ~4076, sigma ~64)

typedef unsigned short u16;
typedef unsigned int   u32;
typedef __attribute__((ext_vector_type(8))) short bf8;   // 8 bf16 = 4 VGPRs
typedef __attribute__((ext_vector_type(4))) float f4;

__device__ __forceinline__ float bf2f(u32 u){ union{u32 i; float f;} x; x.i = u << 16; return x.f; }
__device__ __forceinline__ u16 f2bf(float f){
  union{float f; u32 i;} x; x.f = f;
  u32 r = x.i + 0x7FFFu + ((x.i >> 16) & 1u);
  return (u16)(r >> 16);
}
__device__ __forceinline__ u32 pack2(float a, float b){ return (u32)f2bf(a) | ((u32)f2bf(b) << 16); }

// col packing (pre-scaled): attr[0:1] | src<<8 [8:23] | xid<<27 [27:31]
//   hb byte offset  = col & 0x00FFFF00  (row = src, 256 B/row)
//   bond f2 index   = (col & 3) << 6
//   atom row (L0)   = (u32)col >> 27
// sentinel: src=NN, xid=31  ->  (NN<<8) | (31u<<27)

// ---------------- prologue A: init h/deg/gcur + hb sentinel | wprep ----------------
__global__ void k_pre(const int* __restrict__ x_ids, const float* __restrict__ atom_emb,
                      float* __restrict__ h, u32* __restrict__ hb, int* __restrict__ deg,
                      const float* __restrict__ W1, const float* __restrict__ W2,
                      u16* __restrict__ wt, int* __restrict__ gcur){
  int bid = blockIdx.x, tid = threadIdx.x;
  if (bid < 5000){                                // init: NN*32 items (4 feats/thread)
    int idx = bid * 256 + tid;
    if (idx < NN) deg[idx] = 0;
    if (idx < 160) gcur[idx] = 0;
    if (idx < 32){ uint2 s; s.x = 0xFF80FF80u; s.y = 0xFF80FF80u;  // dummy node row: -inf
      ((uint2*)(hb + NN * 64))[idx] = s; }
    int n = idx >> 5, d4 = idx & 31;
    float4 v = ((const float4*)(atom_emb + x_ids[n] * DD))[d4];
    ((float4*)h)[idx] = v;
  } else {                                        // wprep: 10*16384 items
    int idx = (bid - 5000) * 256 + tid;
    int m = idx >> 14, nk = idx & 16383;
    int n = nk >> 7, k = nk & 127;
    const float* src = (m < LL) ? (W1 + m * 16384) : (W2 + (m - LL) * 16384);
    wt[idx] = f2bf(src[k * DD + n]);
  }
}

// ---------------- prologue B: count degrees + bucket edges ----------------
__global__ __launch_bounds__(1024) void k_bin(const int* __restrict__ ei, const int* __restrict__ ea,
                                              int* __restrict__ deg, int* __restrict__ gcur,
                                              u32* __restrict__ store){
  __shared__ int l_cnt[160];
  __shared__ int l_base[160];
  int tid = threadIdx.x;
  if (tid < 160) l_cnt[tid] = 0;
  __syncthreads();
  int e0 = blockIdx.x * 4096;                     // 157 x 4096 >= EE
  u32 rec[4]; int rb[4], rr[4];
  #pragma unroll
  for (int j = 0; j < 4; ++j){
    int e = e0 + j * 1024 + tid;
    rb[j] = -1;
    if (e < EE){
      int dst = ei[EE + e];
      atomicAdd(&deg[dst], 1);
      int b = dst >> 8;
      rb[j] = b;
      rr[j] = atomicAdd(&l_cnt[b], 1);
      rec[j] = (u32)ei[e] | ((u32)ea[e] << 16) | ((u32)(dst & 255) << 18);
    }
  }
  __syncthreads();
  if (tid < 160) l_base[tid] = atomicAdd(&gcur[tid], l_cnt[tid]);
  __syncthreads();
  #pragma unroll
  for (int j = 0; j < 4; ++j)
    if (rb[j] >= 0)
      store[rb[j] * CAP + l_base[rb[j]] + rr[j]] = rec[j];
}

// phase 1: per-block exclusive scan of degrees PADDED TO x8 + block totals (40 blocks x 1024)
__global__ void k_scan1(const int* __restrict__ deg, int* __restrict__ rs, int* __restrict__ bsum){
  __shared__ int buf[1024];
  int tid = threadIdx.x;
  int i = blockIdx.x * 1024 + tid;
  int dv = (i < NN) ? deg[i] : 0;
  int v = (dv + 7) & ~7;                         // pad each segment to x8 (16-wide gather groups)
  buf[tid] = v;
  __syncthreads();
  for (int off = 1; off < 1024; off <<= 1){
    int t = (tid >= off) ? buf[tid - off] : 0;
    __syncthreads();
    buf[tid] += t;
    __syncthreads();
  }
  int incl = buf[tid];
  if (i < NN) rs[i] = incl - v;                  // chunk-local exclusive
  if (tid == 1023) bsum[blockIdx.x] = incl;
}

// ---------------- place2: scan2-inline + scatter (pre-scaled packing) + sentinel + stats1 zero ----------------
__global__ __launch_bounds__(1024) void k_place2(const u32* __restrict__ store, const int* __restrict__ gcur,
                                                 const int* __restrict__ rs, int* __restrict__ rs2,
                                                 int* __restrict__ col, const int* __restrict__ bsum,
                                                 float* __restrict__ stats1, const int* __restrict__ x_ids){
  __shared__ int l_cur[256];
  __shared__ int s_choff[41];
  int b = blockIdx.x, tid = threadIdx.x;
  if (b == 0){ stats1[tid] = 0.f; stats1[1024 + tid] = 0.f; }
  if (tid < 64){
    int v = (tid < 40) ? bsum[tid] : 0;
    #pragma unroll
    for (int off = 1; off < 64; off <<= 1){
      int t = __shfl_up(v, off, 64);
      if (tid >= off) v += t;
    }
    if (tid < 40){
      s_choff[tid] = v - bsum[tid];              // exclusive chunk offset
      if (tid == 39) s_choff[40] = v;            // padded total
    }
  }
  __syncthreads();
  int n0 = b << 8;
  if (tid < 256){
    int n = n0 + tid;
    if (n < NN){
      int g = rs[n] + s_choff[n >> 10];
      l_cur[tid] = g;
      rs2[n] = g;
    }
  }
  if (b == NB - 1 && tid == 0) rs2[NN] = s_choff[40];
  __syncthreads();
  int cnt = gcur[b];
  for (int r = tid; r < cnt; r += 1024){
    u32 rec = store[b * CAP + r];
    int dl = rec >> 18;
    int src = (int)(rec & 0xFFFFu);
    int attr = (int)((rec >> 16) & 3u);
    u32 xid = (u32)x_ids[src];                   // 0..27, L2-resident table
    int pos = atomicAdd(&l_cur[dl], 1);
    col[pos] = (int)(((u32)src << 8) | (u32)attr | (xid << 27));
  }
  __syncthreads();
  if (tid < 256){                                 // pad gaps with sentinel (dummy node NN, xid 31)
    int n = n0 + tid;
    if (n < NN){
      int e = l_cur[tid];
      int end = (n + 1 < NN) ? (rs[n + 1] + s_choff[(n + 1) >> 10]) : s_choff[40];
      u32 sent = ((u32)NN << 8) | (31u << 27);
      for (; e < end; ++e) col[e] = (int)sent;
    }
  }
}

// ---------------- FUSED gather + GEMM1 ----------------
// 16 rows/block, grid 2500 (tests residency: per-wave chains unchanged, 2x blocks available).
// 16-outstanding gather preserved (round-2 showed 8-outstanding costs ~20%).
// Self term from hb (bf16) for l>=1: z is f2bf-rounded right after, so error is sub-rounding.
// L0: gather sources come from the 32-row LDS atom table (rows 28..31 = -inf) instead of hb.
template<bool L0>
__global__ __launch_bounds__(256, 4) void k_gg(
    const float* __restrict__ h, const u32* __restrict__ hb,
    const int* __restrict__ row_start, const int* __restrict__ col,
    const float* __restrict__ bond_l, const float* __restrict__ eps_l,
    const u16* __restrict__ Wt, const float* __restrict__ bias,
    u16* __restrict__ out, float* __restrict__ osum, float* __restrict__ stats2,
    const float* __restrict__ atom_emb){
  __shared__ u16 sA[16 * 136];
  __shared__ float2 s_bond[4 * 64];
  __shared__ float s_eps;
  __shared__ float s_sum[DD], s_sq[DD];
  __shared__ u32 s_atom[L0 ? 32 * 64 : 64];       // L0 only: 32 rows x 128 bf16
  int tid = threadIdx.x;
  if (blockIdx.x == 0){                           // zero stats2 for this layer
    #pragma unroll
    for (int j = 0; j < 8; ++j) stats2[j * 256 + tid] = 0.f;
  }
  if (tid < 256) s_bond[tid] = ((const float2*)bond_l)[tid];
  if (tid == 0) s_eps = 1.0f + eps_l[0];
  if (tid < DD){ s_sum[tid] = 0.f; s_sq[tid] = 0.f; }
  if (L0){
    #pragma unroll
    for (int j = 0; j < 8; ++j){
      int idx = j * 256 + tid;                    // row = idx>>6, pair = idx&63
      int row = idx >> 6, pr = idx & 63;
      u32 v = 0xFF80FF80u;
      if (row < 28){
        float2 ae = ((const float2*)(atom_emb + row * DD))[pr];
        v = pack2(ae.x, ae.y);
      }
      s_atom[idx] = v;
    }
  }
  __syncthreads();
  int w = tid >> 6, lane = tid & 63;
  int lane4 = lane << 2;
  const char* hbB = (const char*)hb;
  int vbase = blockIdx.x * 16 + w * 4;
  int sprev = __builtin_amdgcn_readfirstlane(row_start[vbase]);
  for (int j = 0; j < 4; ++j){
    int v = vbase + j;
    int send = __builtin_amdgcn_readfirstlane(row_start[v + 1]);  // multiple of 8
    int i = sprev; sprev = send;
    float accx[4] = {0.f, 0.f, 0.f, 0.f};
    float accy[4] = {0.f, 0.f, 0.f, 0.f};
    for (; i + 16 <= send; i += 16){              // 16 outstanding loads
      int4 c0 = *(const int4*)(col + i);
      int4 c1 = *(const int4*)(col + i + 4);
      int4 c2 = *(const int4*)(col + i + 8);
      int4 c3 = *(const int4*)(col + i + 12);
      int id[16] = {c0.x, c0.y, c0.z, c0.w, c1.x, c1.y, c1.z, c1.w,
                    c2.x, c2.y, c2.z, c2.w, c3.x, c3.y, c3.z, c3.w};
      u32 hx[16];
      #pragma unroll
      for (int q = 0; q < 16; ++q)
        hx[q] = L0 ? s_atom[(((u32)id[q] >> 27) << 6) + lane]
                   : *(const u32*)(hbB + (id[q] & 0x00FFFF00) + lane4);
      #pragma unroll
      for (int q = 0; q < 16; ++q){
        float2 bb = s_bond[((id[q] & 3) << 6) + lane];
        accx[q & 3] += fmaxf(bf2f(hx[q] & 0xFFFFu) + bb.x, 0.f);
        accy[q & 3] += fmaxf(bf2f(hx[q] >> 16)     + bb.y, 0.f);
      }
    }
    if (i < send){                                // exactly one 8-group remains
      int4 c0 = *(const int4*)(col + i);
      int4 c1 = *(const int4*)(col + i + 4);
      int id[8] = {c0.x, c0.y, c0.z, c0.w, c1.x, c1.y, c1.z, c1.w};
      u32 hx[8];
      #pragma unroll
      for (int q = 0; q < 8; ++q)
        hx[q] = L0 ? s_atom[(((u32)id[q] >> 27) << 6) + lane]
                   : *(const u32*)(hbB + (id[q] & 0x00FFFF00) + lane4);
      #pragma unroll
      for (int q = 0; q < 8; ++q){
        float2 bb = s_bond[((id[q] & 3) << 6) + lane];
        accx[q & 3] += fmaxf(bf2f(hx[q] & 0xFFFFu) + bb.x, 0.f);
        accy[q & 3] += fmaxf(bf2f(hx[q] >> 16)     + bb.y, 0.f);
      }
    }
    float hvx, hvy;
    if (L0){
      float2 hv = ((const float2*)h)[v * 64 + lane];
      hvx = hv.x; hvy = hv.y;
    } else {
      u32 hp = hb[v * 64 + lane];                 // bf16 mirror; z is rounded to bf16 anyway
      hvx = bf2f(hp & 0xFFFFu); hvy = bf2f(hp >> 16);
    }
    u32 zp = pack2(s_eps * hvx + (accx[0] + accx[1]) + (accx[2] + accx[3]),
                   s_eps * hvy + (accy[0] + accy[1]) + (accy[2] + accy[3]));
    *(u32*)(sA + (w * 4 + j) * 136 + lane * 2) = zp;
  }
  int lr = lane & 15, lk = lane >> 4;
  bf8 bfr[2][4];
  #pragma unroll
  for (int nt = 0; nt < 2; ++nt){
    int n = w * 32 + nt * 16 + lr;
    #pragma unroll
    for (int kt = 0; kt < 4; ++kt)
      bfr[nt][kt] = *(const bf8*)(Wt + n * DD + kt * 32 + lk * 8);
  }
  __syncthreads();
  f4 acc[2];
  acc[0] = (f4){0.f, 0.f, 0.f, 0.f};
  acc[1] = (f4){0.f, 0.f, 0.f, 0.f};
  #pragma unroll
  for (int kt = 0; kt < 4; ++kt){
    bf8 a0 = *(const bf8*)(sA + lr * 136 + kt * 32 + lk * 8);
    acc[0] = __builtin_amdgcn_mfma_f32_16x16x32_bf16(a0, bfr[0][kt], acc[0], 0, 0, 0);
    acc[1] = __builtin_amdgcn_mfma_f32_16x16x32_bf16(a0, bfr[1][kt], acc[1], 0, 0, 0);
  }
  int row0 = blockIdx.x * 16;
  #pragma unroll
  for (int nt = 0; nt < 2; ++nt){
    int colg = w * 32 + nt * 16 + lr;
    float bv = bias[colg];
    float cs = 0.f, cq = 0.f;
    #pragma unroll
    for (int r = 0; r < 4; ++r){
      u16 yb = f2bf(acc[nt][r] + bv);
      float yr = bf2f(yb);
      out[(row0 + lk * 4 + r) * DD + colg] = yb;
      cs += yr; cq += yr * yr;
    }
    atomicAdd(&s_sum[colg], cs);
    atomicAdd(&s_sq[colg], cq);
  }
  __syncthreads();
  float* slice = osum + (blockIdx.x & 7) * 256;
  if (tid < DD){
    atomicAdd(&slice[tid],      s_sum[tid]);
    atomicAdd(&slice[DD + tid], s_sq[tid]);
  }
}

// ---------------- GEMM2: BN1+ReLU on input, MFMA @W2+b2, bf16 out + sliced stats2 ----------------
__global__ __launch_bounds__(256) void k_gemm2(const u16* __restrict__ Asrc,
    const u16* __restrict__ Wt, const float* __restrict__ bias,
    const float* __restrict__ stats_in,       // 8 slices x [sum128|sq128]
    const float* __restrict__ g, const float* __restrict__ bt,
    u16* __restrict__ out, float* __restrict__ osum){
  __shared__ u16 sA[32 * 136];
  __shared__ float s_scale[DD], s_shift[DD];
  __shared__ float s_sum[DD], s_sq[DD];
  int tid = threadIdx.x;
  int row0 = blockIdx.x * 32;
  if (tid < DD){
    s_sum[tid] = 0.f; s_sq[tid] = 0.f;
    float s = 0.f, q = 0.f;
    #pragma unroll
    for (int s8 = 0; s8 < 8; ++s8){
      s += stats_in[s8 * 256 + tid];
      q += stats_in[s8 * 256 + DD + tid];
    }
    float m   = s * (1.0f / NN);
    float var = q * (1.0f / NN) - m * m;
    float inv = rsqrtf(var + 1e-5f);
    float sc  = inv * g[tid];
    s_scale[tid] = sc;
    s_shift[tid] = bt[tid] - m * sc;
  }
  __syncthreads();
  #pragma unroll
  for (int c0 = 0; c0 < 2; ++c0){
    int c = tid + c0 * 256;
    int row = c >> 4, off = (c & 15) * 8;
    uint4 v = *(const uint4*)(Asrc + (row0 + row) * DD + off);
    u32 wv[4] = {v.x, v.y, v.z, v.w};
    union { u16 o[8]; uint4 v; } u;
    #pragma unroll
    for (int j = 0; j < 4; ++j){
      float y0 = bf2f(wv[j] & 0xFFFFu) * s_scale[off + 2*j]     + s_shift[off + 2*j];
      float y1 = bf2f(wv[j] >> 16)     * s_scale[off + 2*j + 1] + s_shift[off + 2*j + 1];
      u.o[2*j]     = f2bf(fmaxf(y0, 0.f));
      u.o[2*j + 1] = f2bf(fmaxf(y1, 0.f));
    }
    *(uint4*)(sA + row * 136 + off) = u.v;
  }
  int w = tid >> 6, lane = tid & 63, lr = lane & 15, lk = lane >> 4;
  bf8 bfr[2][4];
  #pragma unroll
  for (int nt = 0; nt < 2; ++nt){
    int n = w * 32 + nt * 16 + lr;
    #pragma unroll
    for (int kt = 0; kt < 4; ++kt)
      bfr[nt][kt] = *(const bf8*)(Wt + n * DD + kt * 32 + lk * 8);
  }
  __syncthreads();
  f4 acc[2][2];
  #pragma unroll
  for (int mt = 0; mt < 2; ++mt)
    #pragma unroll
    for (int nt = 0; nt < 2; ++nt) acc[mt][nt] = (f4){0.f, 0.f, 0.f, 0.f};
  #pragma unroll
  for (int kt = 0; kt < 4; ++kt){
    bf8 a0 = *(const bf8*)(sA + lr * 136        + kt * 32 + lk * 8);
    bf8 a1 = *(const bf8*)(sA + (16 + lr) * 136 + kt * 32 + lk * 8);
    acc[0][0] = __builtin_amdgcn_mfma_f32_16x16x32_bf16(a0, bfr[0][kt], acc[0][0], 0, 0, 0);
    acc[0][1] = __builtin_amdgcn_mfma_f32_16x16x32_bf16(a0, bfr[1][kt], acc[0][1], 0, 0, 0);
    acc[1][0] = __builtin_amdgcn_mfma_f32_16x16x32_bf16(a1, bfr[0][kt], acc[1][0], 0, 0, 0);
    acc[1][1] = __builtin_amdgcn_mfma_f32_16x16x32_bf16(a1, bfr[1][kt], acc[1][1], 0, 0, 0);
  }
  #pragma unroll
  for (int nt = 0; nt < 2; ++nt){
    int colg = w * 32 + nt * 16 + lr;
    float bv = bias[colg];
    float cs = 0.f, cq = 0.f;
    #pragma unroll
    for (int mt = 0; mt < 2; ++mt){
      #pragma unroll
      for (int r = 0; r < 4; ++r){
        u16 yb = f2bf(acc[mt][nt][r] + bv);
        float yr = bf2f(yb);
        out[(row0 + mt * 16 + lk * 4 + r) * DD + colg] = yb;
        cs += yr; cq += yr * yr;
      }
    }
    atomicAdd(&s_sum[colg], cs);
    atomicAdd(&s_sq[colg], cq);
  }
  __syncthreads();
  float* slice = osum + (blockIdx.x & 7) * 256;
  if (tid < DD){
    atomicAdd(&slice[tid],      s_sum[tid]);
    atomicAdd(&slice[DD + tid], s_sq[tid]);
  }
}

// ---------------- BN2 (+ReLU except last) + residual; 4 feats/thread; block 0 zeroes stats1 ----------------
// do_relu gates both the ReLU and the hb mirror write (hb is dead after the last layer).
__global__ void k_final(const u32* __restrict__ zf, const float* __restrict__ stats2,
                        const float* __restrict__ gl, const float* __restrict__ bl,
                        float* __restrict__ h, u32* __restrict__ hb, int do_relu,
                        float* __restrict__ stats1){
  __shared__ float s_scale[DD], s_shift[DD];
  int tid = threadIdx.x;
  if (blockIdx.x == 0){                           // zero stats1 for next layer's k_gg
    #pragma unroll
    for (int j = 0; j < 8; ++j) stats1[j * 256 + tid] = 0.f;
  }
  if (tid < DD){
    float s = 0.f, q = 0.f;
    #pragma unroll
    for (int s8 = 0; s8 < 8; ++s8){
      s += stats2[s8 * 256 + tid];
      q += stats2[s8 * 256 + DD + tid];
    }
    float m   = s * (1.0f / NN);
    float var = q * (1.0f / NN) - m * m;
    float inv = rsqrtf(var + 1e-5f);
    float sc  = inv * gl[tid];
    s_scale[tid] = sc;
    s_shift[tid] = bl[tid] - m * sc;
  }
  __syncthreads();
  int idx = blockIdx.x * 256 + tid;           // NN*32 items, 4 feats each
  int j0 = (idx & 31) * 4;
  uint2 zz = ((const uint2*)zf)[idx];
  float val0 = bf2f(zz.x & 0xFFFFu) * s_scale[j0]     + s_shift[j0];
  float val1 = bf2f(zz.x >> 16)     * s_scale[j0 + 1] + s_shift[j0 + 1];
  float val2 = bf2f(zz.y & 0xFFFFu) * s_scale[j0 + 2] + s_shift[j0 + 2];
  float val3 = bf2f(zz.y >> 16)     * s_scale[j0 + 3] + s_shift[j0 + 3];
  if (do_relu){
    val0 = fmaxf(val0, 0.f); val1 = fmaxf(val1, 0.f);
    val2 = fmaxf(val2, 0.f); val3 = fmaxf(val3, 0.f);
  }
  float4 hv = ((float4*)h)[idx];
  hv.x += val0; hv.y += val1; hv.z += val2; hv.w += val3;
  ((float4*)h)[idx] = hv;
  if (do_relu){                                   // last layer: hb is dead, skip the write
    uint2 hp; hp.x = pack2(hv.x, hv.y); hp.y = pack2(hv.z, hv.w);
    ((uint2*)hb)[idx] = hp;
  }
}

extern "C" void kernel_launch(void* const* d_in, const int* in_sizes, int n_in,
                              void* d_out, int out_size, void* d_ws, size_t ws_size,
                              hipStream_t stream) {
  const int*   x_ids      = (const int*)d_in[0];
  const int*   edge_index = (const int*)d_in[1];
  const int*   edge_attr  = (const int*)d_in[2];
  const float* atom_emb   = (const float*)d_in[3];
  const float* bond_emb   = (const float*)d_in[4];
  const float* W1    = (const float*)d_in[5];
  const float* b1    = (const float*)d_in[6];
  const float* g1    = (const float*)d_in[7];
  const float* bt1   = (const float*)d_in[8];
  const float* W2    = (const float*)d_in[9];
  const float* b2    = (const float*)d_in[10];
  const float* eps   = (const float*)d_in[11];
  const float* g_out = (const float*)d_in[12];
  const float* b_out = (const float*)d_in[13];

  float* h   = (float*)d_out;                 // NN*DD fp32 running node state
  u32*   zb  = (u32*)d_ws;                    // prologue: bin store; loop: unused
  u32*   z2b = zb  + NN * 64;                 // NN*64: bf16 gemm1 out
  u32*   zAb = z2b + NN * 64;                 // NN*64: bf16 gemm2 out
  u32*   hb  = zAb + NN * 64;                 // (NN+1)*64: bf16 mirror of h + sentinel row
  u16*   wt  = (u16*)(hb + (NN + 1) * 64);    // 10*16384 bf16 transposed weights
  float* stats = (float*)(wt + 10 * 16384);   // 4096: stats1[0..2047] | stats2[2048..4095]
  int* rs        = (int*)(stats + 4096);      // NN+4 (chunk-local scan)
  int* rs2       = rs + NN + 4;               // NN+4 (finalized row offsets)
  int* deg       = rs2 + NN + 4;
  int* col       = deg + NN;                  // EE + 7*NN (x8-padded)
  int* bsum      = col + EE + 7 * NN;         // 40
  int* gcur      = bsum + 64;                 // 160 bucket cursors

  u32* store = zb;                            // NB*CAP u32 records (5.1 MB; dead before loop)

  k_pre   <<<5640, 256, 0, stream>>>(x_ids, atom_emb, h, hb, deg, W1, W2, wt, gcur);
  k_bin   <<<NB, 1024, 0, stream>>>(edge_index, edge_attr, deg, gcur, store);
  k_scan1 <<<40, 1024, 0, stream>>>(deg, rs, bsum);
  k_place2<<<NB, 1024, 0, stream>>>(store, gcur, rs, rs2, col, bsum, stats, x_ids);

  for (int l = 0; l < LL; ++l){
    if (l == 0)
      k_gg<true> <<<NN / 16, 256, 0, stream>>>(h, hb, rs2, col,
                                               bond_emb + l * 4 * DD, eps + l,
                                               wt + l * 16384, b1 + l * DD,
                                               (u16*)z2b, stats, stats + 2048, atom_emb);
    else
      k_gg<false><<<NN / 16, 256, 0, stream>>>(h, hb, rs2, col,
                                               bond_emb + l * 4 * DD, eps + l,
                                               wt + l * 16384, b1 + l * DD,
                                               (u16*)z2b, stats, stats + 2048, atom_emb);
    k_gemm2<<<NN / 32, 256, 0, stream>>>((const u16*)z2b, wt + (LL + l) * 16384, b2 + l * DD,
                                         stats, g1 + l * DD, bt1 + l * DD,
                                         (u16*)zAb, stats + 2048);
    k_final<<<NN * 32 / 256, 256, 0, stream>>>(zAb, stats + 2048,
                                               g_out + l * DD, b_out + l * DD,
                                               h, hb, (l < LL - 1) ? 1 : 0, stats);
  }
}

// Round 6
// 441.021 us; speedup vs baseline: 1.2846x; 1.0618x over previous
//
#include <hip/hip_runtime.h>

#define NN 40000
#define EE 640000
#define DD 128
#define LL 5
#define NB 157          // buckets of 256 dst nodes
#define CAP 8192        // slots per bucket (mean ~4076, sigma ~64)

typedef unsigned short u16;
typedef unsigned int   u32;
typedef __attribute__((ext_vector_type(8))) short bf8;   // 8 bf16 = 4 VGPRs
typedef __attribute__((ext_vector_type(4))) float f4;

__device__ __forceinline__ float bf2f(u32 u){ union{u32 i; float f;} x; x.i = u << 16; return x.f; }
__device__ __forceinline__ u16 f2bf(float f){
  union{float f; u32 i;} x; x.f = f;
  u32 r = x.i + 0x7FFFu + ((x.i >> 16) & 1u);
  return (u16)(r >> 16);
}
__device__ __forceinline__ u32 pack2(float a, float b){ return (u32)f2bf(a) | ((u32)f2bf(b) << 16); }

// col packing (pre-scaled): attr[0:1] | src<<8 [8:23] | xid<<27 [27:31]
//   hb byte offset  = col & 0x00FFFF00  (row = src, 256 B/row)
//   bond f2 index   = (col & 3) << 6
//   atom row (L0)   = (u32)col >> 27
// sentinel: src=NN, xid=31  ->  (NN<<8) | (31u<<27)

// ---------------- prologue A: init h/deg/gcur + hb sentinel | wprep ----------------
__global__ void k_pre(const int* __restrict__ x_ids, const float* __restrict__ atom_emb,
                      float* __restrict__ h, u32* __restrict__ hb, int* __restrict__ deg,
                      const float* __restrict__ W1, const float* __restrict__ W2,
                      u16* __restrict__ wt, int* __restrict__ gcur){
  int bid = blockIdx.x, tid = threadIdx.x;
  if (bid < 5000){                                // init: NN*32 items (4 feats/thread)
    int idx = bid * 256 + tid;
    if (idx < NN) deg[idx] = 0;
    if (idx < 160) gcur[idx] = 0;
    if (idx < 32){ uint2 s; s.x = 0xFF80FF80u; s.y = 0xFF80FF80u;  // dummy node row: -inf
      ((uint2*)(hb + NN * 64))[idx] = s; }
    int n = idx >> 5, d4 = idx & 31;
    float4 v = ((const float4*)(atom_emb + x_ids[n] * DD))[d4];
    ((float4*)h)[idx] = v;
  } else {                                        // wprep: 10*16384 items
    int idx = (bid - 5000) * 256 + tid;
    int m = idx >> 14, nk = idx & 16383;
    int n = nk >> 7, k = nk & 127;
    const float* src = (m < LL) ? (W1 + m * 16384) : (W2 + (m - LL) * 16384);
    wt[idx] = f2bf(src[k * DD + n]);
  }
}

// ---------------- prologue B: count degrees + bucket edges ----------------
__global__ __launch_bounds__(1024) void k_bin(const int* __restrict__ ei, const int* __restrict__ ea,
                                              int* __restrict__ deg, int* __restrict__ gcur,
                                              u32* __restrict__ store){
  __shared__ int l_cnt[160];
  __shared__ int l_base[160];
  int tid = threadIdx.x;
  if (tid < 160) l_cnt[tid] = 0;
  __syncthreads();
  int e0 = blockIdx.x * 4096;                     // 157 x 4096 >= EE
  u32 rec[4]; int rb[4], rr[4];
  #pragma unroll
  for (int j = 0; j < 4; ++j){
    int e = e0 + j * 1024 + tid;
    rb[j] = -1;
    if (e < EE){
      int dst = ei[EE + e];
      atomicAdd(&deg[dst], 1);
      int b = dst >> 8;
      rb[j] = b;
      rr[j] = atomicAdd(&l_cnt[b], 1);
      rec[j] = (u32)ei[e] | ((u32)ea[e] << 16) | ((u32)(dst & 255) << 18);
    }
  }
  __syncthreads();
  if (tid < 160) l_base[tid] = atomicAdd(&gcur[tid], l_cnt[tid]);
  __syncthreads();
  #pragma unroll
  for (int j = 0; j < 4; ++j)
    if (rb[j] >= 0)
      store[rb[j] * CAP + l_base[rb[j]] + rr[j]] = rec[j];
}

// phase 1: per-block exclusive scan of degrees PADDED TO x8 + block totals (40 blocks x 1024)
__global__ void k_scan1(const int* __restrict__ deg, int* __restrict__ rs, int* __restrict__ bsum){
  __shared__ int buf[1024];
  int tid = threadIdx.x;
  int i = blockIdx.x * 1024 + tid;
  int dv = (i < NN) ? deg[i] : 0;
  int v = (dv + 7) & ~7;                         // pad each segment to x8 (8-edge groups)
  buf[tid] = v;
  __syncthreads();
  for (int off = 1; off < 1024; off <<= 1){
    int t = (tid >= off) ? buf[tid - off] : 0;
    __syncthreads();
    buf[tid] += t;
    __syncthreads();
  }
  int incl = buf[tid];
  if (i < NN) rs[i] = incl - v;                  // chunk-local exclusive
  if (tid == 1023) bsum[blockIdx.x] = incl;
}

// ---------------- place2: scan2-inline + scatter (pre-scaled packing) + sentinel + stats1 zero ----------------
__global__ __launch_bounds__(1024) void k_place2(const u32* __restrict__ store, const int* __restrict__ gcur,
                                                 const int* __restrict__ rs, int* __restrict__ rs2,
                                                 int* __restrict__ col, const int* __restrict__ bsum,
                                                 float* __restrict__ stats1, const int* __restrict__ x_ids){
  __shared__ int l_cur[256];
  __shared__ int s_choff[41];
  int b = blockIdx.x, tid = threadIdx.x;
  if (b == 0){ stats1[tid] = 0.f; stats1[1024 + tid] = 0.f; }
  if (tid < 64){
    int v = (tid < 40) ? bsum[tid] : 0;
    #pragma unroll
    for (int off = 1; off < 64; off <<= 1){
      int t = __shfl_up(v, off, 64);
      if (tid >= off) v += t;
    }
    if (tid < 40){
      s_choff[tid] = v - bsum[tid];              // exclusive chunk offset
      if (tid == 39) s_choff[40] = v;            // padded total
    }
  }
  __syncthreads();
  int n0 = b << 8;
  if (tid < 256){
    int n = n0 + tid;
    if (n < NN){
      int g = rs[n] + s_choff[n >> 10];
      l_cur[tid] = g;
      rs2[n] = g;
    }
  }
  if (b == NB - 1 && tid == 0) rs2[NN] = s_choff[40];
  __syncthreads();
  int cnt = gcur[b];
  for (int r = tid; r < cnt; r += 1024){
    u32 rec = store[b * CAP + r];
    int dl = rec >> 18;
    int src = (int)(rec & 0xFFFFu);
    int attr = (int)((rec >> 16) & 3u);
    u32 xid = (u32)x_ids[src];                   // 0..27, L2-resident table
    int pos = atomicAdd(&l_cur[dl], 1);
    col[pos] = (int)(((u32)src << 8) | (u32)attr | (xid << 27));
  }
  __syncthreads();
  if (tid < 256){                                 // pad gaps with sentinel (dummy node NN, xid 31)
    int n = n0 + tid;
    if (n < NN){
      int e = l_cur[tid];
      int end = (n + 1 < NN) ? (rs[n + 1] + s_choff[(n + 1) >> 10]) : s_choff[40];
      u32 sent = ((u32)NN << 8) | (31u << 27);
      for (; e < end; ++e) col[e] = (int)sent;
    }
  }
}

// ---------------- FUSED gather + GEMM1 ----------------
// 32 rows/block (grid 1250, the proven tile). Gather rewritten as a FLAT-EDGE PIPELINE:
// the wave's 8 row-segments are one contiguous x8-padded range; 8-edge groups with
// next-group hb loads issued BEFORE consuming the current group and col prefetched two
// groups ahead. Row boundaries are group-aligned; closed via scalar boundary checks.
// Self term from hb (bf16) for l>=1 (z is f2bf-rounded right after; error sub-rounding).
// L0: gather sources come from the 32-row LDS atom table (rows 28..31 = -inf).
#define GG_LOAD(idv)  (*(const u32*)(hbB + ((idv) & 0x00FFFF00) + lane4))
#define GG_LOADA(idv) s_atom[((((u32)(idv)) >> 27) << 6) + lane]
#define GG_CONS(idv, hxv, k) { float2 bb = s_bond[(((idv) & 3) << 6) + lane]; \
  accx[k] += fmaxf(bf2f((hxv) & 0xFFFFu) + bb.x, 0.f); \
  accy[k] += fmaxf(bf2f((hxv) >> 16)     + bb.y, 0.f); }
#define GG_FIN() { \
  int v = vbase + rr; float hvx, hvy; \
  if (L0){ float2 hv = ((const float2*)h)[v * 64 + lane]; hvx = hv.x; hvy = hv.y; } \
  else    { u32 hp = hb[v * 64 + lane]; hvx = bf2f(hp & 0xFFFFu); hvy = bf2f(hp >> 16); } \
  u32 zp = pack2(epsv * hvx + (accx[0] + accx[1]) + (accx[2] + accx[3]), \
                 epsv * hvy + (accy[0] + accy[1]) + (accy[2] + accy[3])); \
  *(u32*)(sA + (w * 8 + rr) * 136 + lane * 2) = zp; \
  accx[0] = accx[1] = accx[2] = accx[3] = 0.f; \
  accy[0] = accy[1] = accy[2] = accy[3] = 0.f; \
  ++rr; send = __builtin_amdgcn_readfirstlane(row_start[vbase + rr + 1]); }

template<bool L0>
__global__ __launch_bounds__(256, 4) void k_gg(
    const float* __restrict__ h, const u32* __restrict__ hb,
    const int* __restrict__ row_start, const int* __restrict__ col,
    const float* __restrict__ bond_l, const float* __restrict__ eps_l,
    const u16* __restrict__ Wt, const float* __restrict__ bias,
    u16* __restrict__ out, float* __restrict__ osum, float* __restrict__ stats2,
    const float* __restrict__ atom_emb){
  __shared__ u16 sA[32 * 136];
  __shared__ float2 s_bond[4 * 64];
  __shared__ float s_eps;
  __shared__ float s_sum[DD], s_sq[DD];
  __shared__ u32 s_atom[L0 ? 32 * 64 : 64];       // L0 only: 32 rows x 128 bf16
  int tid = threadIdx.x;
  if (blockIdx.x == 0){                           // zero stats2 for this layer
    #pragma unroll
    for (int j = 0; j < 8; ++j) stats2[j * 256 + tid] = 0.f;
  }
  if (tid < 256) s_bond[tid] = ((const float2*)bond_l)[tid];
  if (tid == 0) s_eps = 1.0f + eps_l[0];
  if (tid < DD){ s_sum[tid] = 0.f; s_sq[tid] = 0.f; }
  if (L0){
    #pragma unroll
    for (int j = 0; j < 8; ++j){
      int idx = j * 256 + tid;                    // row = idx>>6, pair = idx&63
      int row = idx >> 6, pr = idx & 63;
      u32 v = 0xFF80FF80u;
      if (row < 28){
        float2 ae = ((const float2*)(atom_emb + row * DD))[pr];
        v = pack2(ae.x, ae.y);
      }
      s_atom[idx] = v;
    }
  }
  __syncthreads();
  int w = tid >> 6, lane = tid & 63;
  int lane4 = lane << 2;
  const char* hbB = (const char*)hb;
  int vbase = blockIdx.x * 32 + w * 8;
  float epsv = s_eps;

  float accx[4] = {0.f, 0.f, 0.f, 0.f};
  float accy[4] = {0.f, 0.f, 0.f, 0.f};
  int rr = 0;
  int s0   = __builtin_amdgcn_readfirstlane(row_start[vbase]);
  int s1   = __builtin_amdgcn_readfirstlane(row_start[vbase + 8]);
  int send = __builtin_amdgcn_readfirstlane(row_start[vbase + 1]);

  while (rr < 8 && send == s0) GG_FIN();          // leading empty rows

  if (s0 < s1){
    int4 c0 = *(const int4*)(col + s0);
    int4 c1 = *(const int4*)(col + s0 + 4);
    int cu0 = c0.x, cu1 = c0.y, cu2 = c0.z, cu3 = c0.w;
    int cu4 = c1.x, cu5 = c1.y, cu6 = c1.z, cu7 = c1.w;
    u32 hx0, hx1, hx2, hx3, hx4, hx5, hx6, hx7;
    if (L0){
      hx0 = GG_LOADA(cu0); hx1 = GG_LOADA(cu1); hx2 = GG_LOADA(cu2); hx3 = GG_LOADA(cu3);
      hx4 = GG_LOADA(cu4); hx5 = GG_LOADA(cu5); hx6 = GG_LOADA(cu6); hx7 = GG_LOADA(cu7);
    } else {
      hx0 = GG_LOAD(cu0); hx1 = GG_LOAD(cu1); hx2 = GG_LOAD(cu2); hx3 = GG_LOAD(cu3);
      hx4 = GG_LOAD(cu4); hx5 = GG_LOAD(cu5); hx6 = GG_LOAD(cu6); hx7 = GG_LOAD(cu7);
    }
    int4 n0, n1;
    if (s0 + 8 < s1){ n0 = *(const int4*)(col + s0 + 8); n1 = *(const int4*)(col + s0 + 12); }
    for (int i = s0; i < s1; i += 8){
      bool more = (i + 8 < s1);
      int nd0, nd1, nd2, nd3, nd4, nd5, nd6, nd7;
      u32 nx0, nx1, nx2, nx3, nx4, nx5, nx6, nx7;
      if (more){
        nd0 = n0.x; nd1 = n0.y; nd2 = n0.z; nd3 = n0.w;
        nd4 = n1.x; nd5 = n1.y; nd6 = n1.z; nd7 = n1.w;
        if (L0){                                  // issue next group before consuming current
          nx0 = GG_LOADA(nd0); nx1 = GG_LOADA(nd1); nx2 = GG_LOADA(nd2); nx3 = GG_LOADA(nd3);
          nx4 = GG_LOADA(nd4); nx5 = GG_LOADA(nd5); nx6 = GG_LOADA(nd6); nx7 = GG_LOADA(nd7);
        } else {
          nx0 = GG_LOAD(nd0); nx1 = GG_LOAD(nd1); nx2 = GG_LOAD(nd2); nx3 = GG_LOAD(nd3);
          nx4 = GG_LOAD(nd4); nx5 = GG_LOAD(nd5); nx6 = GG_LOAD(nd6); nx7 = GG_LOAD(nd7);
        }
        if (i + 16 < s1){                         // prefetch col two groups ahead
          n0 = *(const int4*)(col + i + 16);
          n1 = *(const int4*)(col + i + 20);
        }
      }
      GG_CONS(cu0, hx0, 0); GG_CONS(cu1, hx1, 1); GG_CONS(cu2, hx2, 2); GG_CONS(cu3, hx3, 3);
      GG_CONS(cu4, hx4, 0); GG_CONS(cu5, hx5, 1); GG_CONS(cu6, hx6, 2); GG_CONS(cu7, hx7, 3);
      int e = i + 8;
      while (rr < 8 && send == e) GG_FIN();       // close rows ending at this group
      if (more){
        cu0 = nd0; cu1 = nd1; cu2 = nd2; cu3 = nd3;
        cu4 = nd4; cu5 = nd5; cu6 = nd6; cu7 = nd7;
        hx0 = nx0; hx1 = nx1; hx2 = nx2; hx3 = nx3;
        hx4 = nx4; hx5 = nx5; hx6 = nx6; hx7 = nx7;
      }
    }
  }
  while (rr < 8) GG_FIN();                        // safety (all rows already closed)

  int lr = lane & 15, lk = lane >> 4;
  bf8 bfr[2][4];
  #pragma unroll
  for (int nt = 0; nt < 2; ++nt){
    int n = w * 32 + nt * 16 + lr;
    #pragma unroll
    for (int kt = 0; kt < 4; ++kt)
      bfr[nt][kt] = *(const bf8*)(Wt + n * DD + kt * 32 + lk * 8);
  }
  __syncthreads();
  f4 acc[2][2];
  #pragma unroll
  for (int mt = 0; mt < 2; ++mt)
    #pragma unroll
    for (int nt = 0; nt < 2; ++nt) acc[mt][nt] = (f4){0.f, 0.f, 0.f, 0.f};
  #pragma unroll
  for (int kt = 0; kt < 4; ++kt){
    bf8 a0 = *(const bf8*)(sA + lr * 136        + kt * 32 + lk * 8);
    bf8 a1 = *(const bf8*)(sA + (16 + lr) * 136 + kt * 32 + lk * 8);
    acc[0][0] = __builtin_amdgcn_mfma_f32_16x16x32_bf16(a0, bfr[0][kt], acc[0][0], 0, 0, 0);
    acc[0][1] = __builtin_amdgcn_mfma_f32_16x16x32_bf16(a0, bfr[1][kt], acc[0][1], 0, 0, 0);
    acc[1][0] = __builtin_amdgcn_mfma_f32_16x16x32_bf16(a1, bfr[0][kt], acc[1][0], 0, 0, 0);
    acc[1][1] = __builtin_amdgcn_mfma_f32_16x16x32_bf16(a1, bfr[1][kt], acc[1][1], 0, 0, 0);
  }
  int row0 = blockIdx.x * 32;
  #pragma unroll
  for (int nt = 0; nt < 2; ++nt){
    int colg = w * 32 + nt * 16 + lr;
    float bv = bias[colg];
    float cs = 0.f, cq = 0.f;
    #pragma unroll
    for (int mt = 0; mt < 2; ++mt){
      #pragma unroll
      for (int r = 0; r < 4; ++r){
        u16 yb = f2bf(acc[mt][nt][r] + bv);
        float yr = bf2f(yb);
        out[(row0 + mt * 16 + lk * 4 + r) * DD + colg] = yb;
        cs += yr; cq += yr * yr;
      }
    }
    atomicAdd(&s_sum[colg], cs);
    atomicAdd(&s_sq[colg], cq);
  }
  __syncthreads();
  float* slice = osum + (blockIdx.x & 7) * 256;
  if (tid < DD){
    atomicAdd(&slice[tid],      s_sum[tid]);
    atomicAdd(&slice[DD + tid], s_sq[tid]);
  }
}
#undef GG_LOAD
#undef GG_LOADA
#undef GG_CONS
#undef GG_FIN

// ---------------- GEMM2: BN1+ReLU on input, MFMA @W2+b2, bf16 out + sliced stats2 ----------------
__global__ __launch_bounds__(256) void k_gemm2(const u16* __restrict__ Asrc,
    const u16* __restrict__ Wt, const float* __restrict__ bias,
    const float* __restrict__ stats_in,       // 8 slices x [sum128|sq128]
    const float* __restrict__ g, const float* __restrict__ bt,
    u16* __restrict__ out, float* __restrict__ osum){
  __shared__ u16 sA[32 * 136];
  __shared__ float s_scale[DD], s_shift[DD];
  __shared__ float s_sum[DD], s_sq[DD];
  int tid = threadIdx.x;
  int row0 = blockIdx.x * 32;
  if (tid < DD){
    s_sum[tid] = 0.f; s_sq[tid] = 0.f;
    float s = 0.f, q = 0.f;
    #pragma unroll
    for (int s8 = 0; s8 < 8; ++s8){
      s += stats_in[s8 * 256 + tid];
      q += stats_in[s8 * 256 + DD + tid];
    }
    float m   = s * (1.0f / NN);
    float var = q * (1.0f / NN) - m * m;
    float inv = rsqrtf(var + 1e-5f);
    float sc  = inv * g[tid];
    s_scale[tid] = sc;
    s_shift[tid] = bt[tid] - m * sc;
  }
  __syncthreads();
  #pragma unroll
  for (int c0 = 0; c0 < 2; ++c0){
    int c = tid + c0 * 256;
    int row = c >> 4, off = (c & 15) * 8;
    uint4 v = *(const uint4*)(Asrc + (row0 + row) * DD + off);
    u32 wv[4] = {v.x, v.y, v.z, v.w};
    union { u16 o[8]; uint4 v; } u;
    #pragma unroll
    for (int j = 0; j < 4; ++j){
      float y0 = bf2f(wv[j] & 0xFFFFu) * s_scale[off + 2*j]     + s_shift[off + 2*j];
      float y1 = bf2f(wv[j] >> 16)     * s_scale[off + 2*j + 1] + s_shift[off + 2*j + 1];
      u.o[2*j]     = f2bf(fmaxf(y0, 0.f));
      u.o[2*j + 1] = f2bf(fmaxf(y1, 0.f));
    }
    *(uint4*)(sA + row * 136 + off) = u.v;
  }
  int w = tid >> 6, lane = tid & 63, lr = lane & 15, lk = lane >> 4;
  bf8 bfr[2][4];
  #pragma unroll
  for (int nt = 0; nt < 2; ++nt){
    int n = w * 32 + nt * 16 + lr;
    #pragma unroll
    for (int kt = 0; kt < 4; ++kt)
      bfr[nt][kt] = *(const bf8*)(Wt + n * DD + kt * 32 + lk * 8);
  }
  __syncthreads();
  f4 acc[2][2];
  #pragma unroll
  for (int mt = 0; mt < 2; ++mt)
    #pragma unroll
    for (int nt = 0; nt < 2; ++nt) acc[mt][nt] = (f4){0.f, 0.f, 0.f, 0.f};
  #pragma unroll
  for (int kt = 0; kt < 4; ++kt){
    bf8 a0 = *(const bf8*)(sA + lr * 136        + kt * 32 + lk * 8);
    bf8 a1 = *(const bf8*)(sA + (16 + lr) * 136 + kt * 32 + lk * 8);
    acc[0][0] = __builtin_amdgcn_mfma_f32_16x16x32_bf16(a0, bfr[0][kt], acc[0][0], 0, 0, 0);
    acc[0][1] = __builtin_amdgcn_mfma_f32_16x16x32_bf16(a0, bfr[1][kt], acc[0][1], 0, 0, 0);
    acc[1][0] = __builtin_amdgcn_mfma_f32_16x16x32_bf16(a1, bfr[0][kt], acc[1][0], 0, 0, 0);
    acc[1][1] = __builtin_amdgcn_mfma_f32_16x16x32_bf16(a1, bfr[1][kt], acc[1][1], 0, 0, 0);
  }
  #pragma unroll
  for (int nt = 0; nt < 2; ++nt){
    int colg = w * 32 + nt * 16 + lr;
    float bv = bias[colg];
    float cs = 0.f, cq = 0.f;
    #pragma unroll
    for (int mt = 0; mt < 2; ++mt){
      #pragma unroll
      for (int r = 0; r < 4; ++r){
        u16 yb = f2bf(acc[mt][nt][r] + bv);
        float yr = bf2f(yb);
        out[(row0 + mt * 16 + lk * 4 + r) * DD + colg] = yb;
        cs += yr; cq += yr * yr;
      }
    }
    atomicAdd(&s_sum[colg], cs);
    atomicAdd(&s_sq[colg], cq);
  }
  __syncthreads();
  float* slice = osum + (blockIdx.x & 7) * 256;
  if (tid < DD){
    atomicAdd(&slice[tid],      s_sum[tid]);
    atomicAdd(&slice[DD + tid], s_sq[tid]);
  }
}

// ---------------- BN2 (+ReLU except last) + residual; 4 feats/thread; block 0 zeroes stats1 ----------------
// do_relu gates both the ReLU and the hb mirror write (hb is dead after the last layer).
__global__ void k_final(const u32* __restrict__ zf, const float* __restrict__ stats2,
                        const float* __restrict__ gl, const float* __restrict__ bl,
                        float* __restrict__ h, u32* __restrict__ hb, int do_relu,
                        float* __restrict__ stats1){
  __shared__ float s_scale[DD], s_shift[DD];
  int tid = threadIdx.x;
  if (blockIdx.x == 0){                           // zero stats1 for next layer's k_gg
    #pragma unroll
    for (int j = 0; j < 8; ++j) stats1[j * 256 + tid] = 0.f;
  }
  if (tid < DD){
    float s = 0.f, q = 0.f;
    #pragma unroll
    for (int s8 = 0; s8 < 8; ++s8){
      s += stats2[s8 * 256 + tid];
      q += stats2[s8 * 256 + DD + tid];
    }
    float m   = s * (1.0f / NN);
    float var = q * (1.0f / NN) - m * m;
    float inv = rsqrtf(var + 1e-5f);
    float sc  = inv * gl[tid];
    s_scale[tid] = sc;
    s_shift[tid] = bl[tid] - m * sc;
  }
  __syncthreads();
  int idx = blockIdx.x * 256 + tid;           // NN*32 items, 4 feats each
  int j0 = (idx & 31) * 4;
  uint2 zz = ((const uint2*)zf)[idx];
  float val0 = bf2f(zz.x & 0xFFFFu) * s_scale[j0]     + s_shift[j0];
  float val1 = bf2f(zz.x >> 16)     * s_scale[j0 + 1] + s_shift[j0 + 1];
  float val2 = bf2f(zz.y & 0xFFFFu) * s_scale[j0 + 2] + s_shift[j0 + 2];
  float val3 = bf2f(zz.y >> 16)     * s_scale[j0 + 3] + s_shift[j0 + 3];
  if (do_relu){
    val0 = fmaxf(val0, 0.f); val1 = fmaxf(val1, 0.f);
    val2 = fmaxf(val2, 0.f); val3 = fmaxf(val3, 0.f);
  }
  float4 hv = ((float4*)h)[idx];
  hv.x += val0; hv.y += val1; hv.z += val2; hv.w += val3;
  ((float4*)h)[idx] = hv;
  if (do_relu){                                   // last layer: hb is dead, skip the write
    uint2 hp; hp.x = pack2(hv.x, hv.y); hp.y = pack2(hv.z, hv.w);
    ((uint2*)hb)[idx] = hp;
  }
}

extern "C" void kernel_launch(void* const* d_in, const int* in_sizes, int n_in,
                              void* d_out, int out_size, void* d_ws, size_t ws_size,
                              hipStream_t stream) {
  const int*   x_ids      = (const int*)d_in[0];
  const int*   edge_index = (const int*)d_in[1];
  const int*   edge_attr  = (const int*)d_in[2];
  const float* atom_emb   = (const float*)d_in[3];
  const float* bond_emb   = (const float*)d_in[4];
  const float* W1    = (const float*)d_in[5];
  const float* b1    = (const float*)d_in[6];
  const float* g1    = (const float*)d_in[7];
  const float* bt1   = (const float*)d_in[8];
  const float* W2    = (const float*)d_in[9];
  const float* b2    = (const float*)d_in[10];
  const float* eps   = (const float*)d_in[11];
  const float* g_out = (const float*)d_in[12];
  const float* b_out = (const float*)d_in[13];

  float* h   = (float*)d_out;                 // NN*DD fp32 running node state
  u32*   zb  = (u32*)d_ws;                    // prologue: bin store; loop: unused
  u32*   z2b = zb  + NN * 64;                 // NN*64: bf16 gemm1 out
  u32*   zAb = z2b + NN * 64;                 // NN*64: bf16 gemm2 out
  u32*   hb  = zAb + NN * 64;                 // (NN+1)*64: bf16 mirror of h + sentinel row
  u16*   wt  = (u16*)(hb + (NN + 1) * 64);    // 10*16384 bf16 transposed weights
  float* stats = (float*)(wt + 10 * 16384);   // 4096: stats1[0..2047] | stats2[2048..4095]
  int* rs        = (int*)(stats + 4096);      // NN+4 (chunk-local scan)
  int* rs2       = rs + NN + 4;               // NN+4 (finalized row offsets)
  int* deg       = rs2 + NN + 4;
  int* col       = deg + NN;                  // EE + 7*NN (x8-padded)
  int* bsum      = col + EE + 7 * NN;         // 40
  int* gcur      = bsum + 64;                 // 160 bucket cursors

  u32* store = zb;                            // NB*CAP u32 records (5.1 MB; dead before loop)

  k_pre   <<<5640, 256, 0, stream>>>(x_ids, atom_emb, h, hb, deg, W1, W2, wt, gcur);
  k_bin   <<<NB, 1024, 0, stream>>>(edge_index, edge_attr, deg, gcur, store);
  k_scan1 <<<40, 1024, 0, stream>>>(deg, rs, bsum);
  k_place2<<<NB, 1024, 0, stream>>>(store, gcur, rs, rs2, col, bsum, stats, x_ids);

  for (int l = 0; l < LL; ++l){
    if (l == 0)
      k_gg<true> <<<NN / 32, 256, 0, stream>>>(h, hb, rs2, col,
                                               bond_emb + l * 4 * DD, eps + l,
                                               wt + l * 16384, b1 + l * DD,
                                               (u16*)z2b, stats, stats + 2048, atom_emb);
    else
      k_gg<false><<<NN / 32, 256, 0, stream>>>(h, hb, rs2, col,
                                               bond_emb + l * 4 * DD, eps + l,
                                               wt + l * 16384, b1 + l * DD,
                                               (u16*)z2b, stats, stats + 2048, atom_emb);
    k_gemm2<<<NN / 32, 256, 0, stream>>>((const u16*)z2b, wt + (LL + l) * 16384, b2 + l * DD,
                                         stats, g1 + l * DD, bt1 + l * DD,
                                         (u16*)zAb, stats + 2048);
    k_final<<<NN * 32 / 256, 256, 0, stream>>>(zAb, stats + 2048,
                                               g_out + l * DD, b_out + l * DD,
                                               h, hb, (l < LL - 1) ? 1 : 0, stats);
  }
}

// Round 7
// 425.822 us; speedup vs baseline: 1.3305x; 1.0357x over previous
//
#include <hip/hip_runtime.h>

#define NN 40000
#define EE 640000
#define DD 128
#define LL 5
#define NB 157          // buckets of 256 dst nodes
#define CAP 8192        // slots per bucket (mean ~4076, sigma ~64)

typedef unsigned short u16;
typedef unsigned int   u32;
typedef __attribute__((ext_vector_type(8))) short bf8;   // 8 bf16 = 4 VGPRs
typedef __attribute__((ext_vector_type(4))) float f4;

__device__ __forceinline__ float bf2f(u32 u){ union{u32 i; float f;} x; x.i = u << 16; return x.f; }
__device__ __forceinline__ u16 f2bf(float f){
  union{float f; u32 i;} x; x.f = f;
  u32 r = x.i + 0x7FFFu + ((x.i >> 16) & 1u);
  return (u16)(r >> 16);
}
__device__ __forceinline__ u32 pack2(float a, float b){ return (u32)f2bf(a) | ((u32)f2bf(b) << 16); }

// col packing (pre-scaled): attr[0:1] | src<<8 [8:23] | xid<<27 [27:31]
//   hb byte offset  = col & 0x00FFFF00  (row = src, 256 B/row)
//   bond f2 index   = (col & 3) << 6
//   atom row (L0)   = (u32)col >> 27
// sentinel: src=NN, xid=31  ->  (NN<<8) | (31u<<27)

// ---------------- prologue A: init h/deg/gcur + hb sentinel | wprep ----------------
__global__ void k_pre(const int* __restrict__ x_ids, const float* __restrict__ atom_emb,
                      float* __restrict__ h, u32* __restrict__ hb, int* __restrict__ deg,
                      const float* __restrict__ W1, const float* __restrict__ W2,
                      u16* __restrict__ wt, int* __restrict__ gcur){
  int bid = blockIdx.x, tid = threadIdx.x;
  if (bid < 5000){                                // init: NN*32 items (4 feats/thread)
    int idx = bid * 256 + tid;
    if (idx < NN) deg[idx] = 0;
    if (idx < 160) gcur[idx] = 0;
    if (idx < 32){ uint2 s; s.x = 0xFF80FF80u; s.y = 0xFF80FF80u;  // dummy node row: -inf
      ((uint2*)(hb + NN * 64))[idx] = s; }
    int n = idx >> 5, d4 = idx & 31;
    float4 v = ((const float4*)(atom_emb + x_ids[n] * DD))[d4];
    ((float4*)h)[idx] = v;
  } else {                                        // wprep: 10*16384 items
    int idx = (bid - 5000) * 256 + tid;
    int m = idx >> 14, nk = idx & 16383;
    int n = nk >> 7, k = nk & 127;
    const float* src = (m < LL) ? (W1 + m * 16384) : (W2 + (m - LL) * 16384);
    wt[idx] = f2bf(src[k * DD + n]);
  }
}

// ---------------- prologue B: count degrees + bucket edges ----------------
__global__ __launch_bounds__(1024) void k_bin(const int* __restrict__ ei, const int* __restrict__ ea,
                                              int* __restrict__ deg, int* __restrict__ gcur,
                                              u32* __restrict__ store){
  __shared__ int l_cnt[160];
  __shared__ int l_base[160];
  int tid = threadIdx.x;
  if (tid < 160) l_cnt[tid] = 0;
  __syncthreads();
  int e0 = blockIdx.x * 4096;                     // 157 x 4096 >= EE
  u32 rec[4]; int rb[4], rr[4];
  #pragma unroll
  for (int j = 0; j < 4; ++j){
    int e = e0 + j * 1024 + tid;
    rb[j] = -1;
    if (e < EE){
      int dst = ei[EE + e];
      atomicAdd(&deg[dst], 1);
      int b = dst >> 8;
      rb[j] = b;
      rr[j] = atomicAdd(&l_cnt[b], 1);
      rec[j] = (u32)ei[e] | ((u32)ea[e] << 16) | ((u32)(dst & 255) << 18);
    }
  }
  __syncthreads();
  if (tid < 160) l_base[tid] = atomicAdd(&gcur[tid], l_cnt[tid]);
  __syncthreads();
  #pragma unroll
  for (int j = 0; j < 4; ++j)
    if (rb[j] >= 0)
      store[rb[j] * CAP + l_base[rb[j]] + rr[j]] = rec[j];
}

// phase 1: per-block exclusive scan of degrees PADDED TO x8 + block totals (40 blocks x 1024)
__global__ void k_scan1(const int* __restrict__ deg, int* __restrict__ rs, int* __restrict__ bsum){
  __shared__ int buf[1024];
  int tid = threadIdx.x;
  int i = blockIdx.x * 1024 + tid;
  int dv = (i < NN) ? deg[i] : 0;
  int v = (dv + 7) & ~7;                         // pad each segment to x8 (8-edge groups)
  buf[tid] = v;
  __syncthreads();
  for (int off = 1; off < 1024; off <<= 1){
    int t = (tid >= off) ? buf[tid - off] : 0;
    __syncthreads();
    buf[tid] += t;
    __syncthreads();
  }
  int incl = buf[tid];
  if (i < NN) rs[i] = incl - v;                  // chunk-local exclusive
  if (tid == 1023) bsum[blockIdx.x] = incl;
}

// ---------------- place2: scan2-inline + scatter (pre-scaled packing) + sentinel + stats1 zero ----------------
__global__ __launch_bounds__(1024) void k_place2(const u32* __restrict__ store, const int* __restrict__ gcur,
                                                 const int* __restrict__ rs, int* __restrict__ rs2,
                                                 int* __restrict__ col, const int* __restrict__ bsum,
                                                 float* __restrict__ stats1, const int* __restrict__ x_ids){
  __shared__ int l_cur[256];
  __shared__ int s_choff[41];
  int b = blockIdx.x, tid = threadIdx.x;
  if (b == 0){ stats1[tid] = 0.f; stats1[1024 + tid] = 0.f; }
  if (tid < 64){
    int v = (tid < 40) ? bsum[tid] : 0;
    #pragma unroll
    for (int off = 1; off < 64; off <<= 1){
      int t = __shfl_up(v, off, 64);
      if (tid >= off) v += t;
    }
    if (tid < 40){
      s_choff[tid] = v - bsum[tid];              // exclusive chunk offset
      if (tid == 39) s_choff[40] = v;            // padded total
    }
  }
  __syncthreads();
  int n0 = b << 8;
  if (tid < 256){
    int n = n0 + tid;
    if (n < NN){
      int g = rs[n] + s_choff[n >> 10];
      l_cur[tid] = g;
      rs2[n] = g;
    }
  }
  if (b == NB - 1 && tid == 0) rs2[NN] = s_choff[40];
  __syncthreads();
  int cnt = gcur[b];
  for (int r = tid; r < cnt; r += 1024){
    u32 rec = store[b * CAP + r];
    int dl = rec >> 18;
    int src = (int)(rec & 0xFFFFu);
    int attr = (int)((rec >> 16) & 3u);
    u32 xid = (u32)x_ids[src];                   // 0..27, L2-resident table
    int pos = atomicAdd(&l_cur[dl], 1);
    col[pos] = (int)(((u32)src << 8) | (u32)attr | (xid << 27));
  }
  __syncthreads();
  if (tid < 256){                                 // pad gaps with sentinel (dummy node NN, xid 31)
    int n = n0 + tid;
    if (n < NN){
      int e = l_cur[tid];
      int end = (n + 1 < NN) ? (rs[n + 1] + s_choff[(n + 1) >> 10]) : s_choff[40];
      u32 sent = ((u32)NN << 8) | (31u << 27);
      for (; e < end; ++e) col[e] = (int)sent;
    }
  }
}

// ---------------- FUSED gather + GEMM1 ----------------
// 32 rows/block (grid 1250). DEPTH-2 modulo-scheduled gather pipeline: 3 slots A/B/C,
// loop unrolled x3 so all registers are statically named (no rotation moves, no scratch).
// Issue G_{i+2}'s hb loads before consuming G_i -> each group's loads age ~2 groups of
// VALU before their waitcnt. One-ahead self-term load; row_start via one load + readlane.
// Self term from hb (bf16) for l>=1 (z is f2bf-rounded right after; error sub-rounding).
// L0: gather sources come from the 32-row LDS atom table (rows 28..31 = -inf).
#define GG_LOAD(idv)  (*(const u32*)(hbB + ((idv) & 0x00FFFF00) + lane4))
#define GG_LOADA(idv) s_atom[((((u32)(idv)) >> 27) << 6) + lane]
#define GG_CONS(idv, hxv, k) { float2 bb = s_bond[(((idv) & 3) << 6) + lane]; \
  accx[k] += fmaxf(bf2f((hxv) & 0xFFFFu) + bb.x, 0.f); \
  accy[k] += fmaxf(bf2f((hxv) >> 16)     + bb.y, 0.f); }

#define GG_DECLS(S) int i##S##0,i##S##1,i##S##2,i##S##3,i##S##4,i##S##5,i##S##6,i##S##7; \
  u32 x##S##0,x##S##1,x##S##2,x##S##3,x##S##4,x##S##5,x##S##6,x##S##7;

#define GG_ISSUE(S, POS) { \
  int4 q0 = *(const int4*)(col + (POS)); \
  int4 q1 = *(const int4*)(col + (POS) + 4); \
  i##S##0=q0.x; i##S##1=q0.y; i##S##2=q0.z; i##S##3=q0.w; \
  i##S##4=q1.x; i##S##5=q1.y; i##S##6=q1.z; i##S##7=q1.w; \
  if (L0){ \
    x##S##0=GG_LOADA(i##S##0); x##S##1=GG_LOADA(i##S##1); x##S##2=GG_LOADA(i##S##2); x##S##3=GG_LOADA(i##S##3); \
    x##S##4=GG_LOADA(i##S##4); x##S##5=GG_LOADA(i##S##5); x##S##6=GG_LOADA(i##S##6); x##S##7=GG_LOADA(i##S##7); \
  } else { \
    x##S##0=GG_LOAD(i##S##0); x##S##1=GG_LOAD(i##S##1); x##S##2=GG_LOAD(i##S##2); x##S##3=GG_LOAD(i##S##3); \
    x##S##4=GG_LOAD(i##S##4); x##S##5=GG_LOAD(i##S##5); x##S##6=GG_LOAD(i##S##6); x##S##7=GG_LOAD(i##S##7); \
  } }

#define GG_CONSUME(S) { \
  GG_CONS(i##S##0, x##S##0, 0); GG_CONS(i##S##1, x##S##1, 1); \
  GG_CONS(i##S##2, x##S##2, 2); GG_CONS(i##S##3, x##S##3, 3); \
  GG_CONS(i##S##4, x##S##4, 0); GG_CONS(i##S##5, x##S##5, 1); \
  GG_CONS(i##S##6, x##S##6, 2); GG_CONS(i##S##7, x##S##7, 3); }

#define GG_FIN() { \
  float hvx, hvy; \
  if (L0){ hvx = hsf.x; hvy = hsf.y; } \
  else    { hvx = bf2f(hsb & 0xFFFFu); hvy = bf2f(hsb >> 16); } \
  u32 zp = pack2(epsv * hvx + (accx[0] + accx[1]) + (accx[2] + accx[3]), \
                 epsv * hvy + (accy[0] + accy[1]) + (accy[2] + accy[3])); \
  *(u32*)(sA + (w * 8 + rr) * 136 + lane * 2) = zp; \
  accx[0] = accx[1] = accx[2] = accx[3] = 0.f; \
  accy[0] = accy[1] = accy[2] = accy[3] = 0.f; \
  ++rr; \
  { int nr = (rr < 8) ? rr : 7; \
    if (L0) hsf = ((const float2*)h)[(vbase + nr) * 64 + lane]; \
    else    hsb = hb[(vbase + nr) * 64 + lane]; } \
  send = __builtin_amdgcn_readlane(rsv, (rr < 8 ? rr : 7) + 1); }

#define GG_CLOSE(GIDX) { int e = s0 + ((GIDX) + 1) * 8; while (rr < 8 && send == e) GG_FIN(); }

template<bool L0>
__global__ __launch_bounds__(256, 4) void k_gg(
    const float* __restrict__ h, const u32* __restrict__ hb,
    const int* __restrict__ row_start, const int* __restrict__ col,
    const float* __restrict__ bond_l, const float* __restrict__ eps_l,
    const u16* __restrict__ Wt, const float* __restrict__ bias,
    u16* __restrict__ out, float* __restrict__ osum, float* __restrict__ stats2,
    const float* __restrict__ atom_emb){
  __shared__ u16 sA[32 * 136];
  __shared__ float2 s_bond[4 * 64];
  __shared__ float s_eps;
  __shared__ float s_sum[DD], s_sq[DD];
  __shared__ u32 s_atom[L0 ? 32 * 64 : 64];       // L0 only: 32 rows x 128 bf16
  int tid = threadIdx.x;
  if (blockIdx.x == 0){                           // zero stats2 for this layer
    #pragma unroll
    for (int j = 0; j < 8; ++j) stats2[j * 256 + tid] = 0.f;
  }
  if (tid < 256) s_bond[tid] = ((const float2*)bond_l)[tid];
  if (tid == 0) s_eps = 1.0f + eps_l[0];
  if (tid < DD){ s_sum[tid] = 0.f; s_sq[tid] = 0.f; }
  if (L0){
    #pragma unroll
    for (int j = 0; j < 8; ++j){
      int idx = j * 256 + tid;                    // row = idx>>6, pair = idx&63
      int row = idx >> 6, pr = idx & 63;
      u32 v = 0xFF80FF80u;
      if (row < 28){
        float2 ae = ((const float2*)(atom_emb + row * DD))[pr];
        v = pack2(ae.x, ae.y);
      }
      s_atom[idx] = v;
    }
  }
  __syncthreads();
  int w = tid >> 6, lane = tid & 63;
  int lane4 = lane << 2;
  const char* hbB = (const char*)hb;
  int vbase = blockIdx.x * 32 + w * 8;
  float epsv = s_eps;

  // one vector load covers row_start[vbase .. vbase+8]
  int rl = (lane < 9) ? lane : 8;
  int rsv = row_start[vbase + rl];
  int s0   = __builtin_amdgcn_readlane(rsv, 0);
  int s1   = __builtin_amdgcn_readlane(rsv, 8);
  int send = __builtin_amdgcn_readlane(rsv, 1);

  // one-ahead self-term load (row vbase + rr)
  float2 hsf; u32 hsb;
  if (L0) hsf = ((const float2*)h)[vbase * 64 + lane];
  else    hsb = hb[vbase * 64 + lane];

  float accx[4] = {0.f, 0.f, 0.f, 0.f};
  float accy[4] = {0.f, 0.f, 0.f, 0.f};
  int rr = 0;

  while (rr < 8 && send == s0) GG_FIN();          // leading empty rows

  {
    GG_DECLS(A) GG_DECLS(B) GG_DECLS(C)
    int nG = (s1 - s0) >> 3;
    int g = 0;
    if (nG > 0){
      GG_ISSUE(A, s0);                            // G0
      if (nG > 1) GG_ISSUE(B, s0 + 8);            // G1
      while (g + 3 <= nG){                        // steady state, 3 groups/iter
        if (g + 2 < nG) GG_ISSUE(C, s0 + (g + 2) * 8);
        GG_CONSUME(A); GG_CLOSE(g);
        if (g + 3 < nG) GG_ISSUE(A, s0 + (g + 3) * 8);
        GG_CONSUME(B); GG_CLOSE(g + 1);
        if (g + 4 < nG) GG_ISSUE(B, s0 + (g + 4) * 8);
        GG_CONSUME(C); GG_CLOSE(g + 2);
        g += 3;
      }
      if (g < nG){ GG_CONSUME(A); GG_CLOSE(g); ++g; }
      if (g < nG){ GG_CONSUME(B); GG_CLOSE(g); ++g; }
    }
  }
  while (rr < 8) GG_FIN();                        // safety (all rows already closed)

  int lr = lane & 15, lk = lane >> 4;
  bf8 bfr[2][4];
  #pragma unroll
  for (int nt = 0; nt < 2; ++nt){
    int n = w * 32 + nt * 16 + lr;
    #pragma unroll
    for (int kt = 0; kt < 4; ++kt)
      bfr[nt][kt] = *(const bf8*)(Wt + n * DD + kt * 32 + lk * 8);
  }
  __syncthreads();
  f4 acc[2][2];
  #pragma unroll
  for (int mt = 0; mt < 2; ++mt)
    #pragma unroll
    for (int nt = 0; nt < 2; ++nt) acc[mt][nt] = (f4){0.f, 0.f, 0.f, 0.f};
  #pragma unroll
  for (int kt = 0; kt < 4; ++kt){
    bf8 a0 = *(const bf8*)(sA + lr * 136        + kt * 32 + lk * 8);
    bf8 a1 = *(const bf8*)(sA + (16 + lr) * 136 + kt * 32 + lk * 8);
    acc[0][0] = __builtin_amdgcn_mfma_f32_16x16x32_bf16(a0, bfr[0][kt], acc[0][0], 0, 0, 0);
    acc[0][1] = __builtin_amdgcn_mfma_f32_16x16x32_bf16(a0, bfr[1][kt], acc[0][1], 0, 0, 0);
    acc[1][0] = __builtin_amdgcn_mfma_f32_16x16x32_bf16(a1, bfr[0][kt], acc[1][0], 0, 0, 0);
    acc[1][1] = __builtin_amdgcn_mfma_f32_16x16x32_bf16(a1, bfr[1][kt], acc[1][1], 0, 0, 0);
  }
  int row0 = blockIdx.x * 32;
  #pragma unroll
  for (int nt = 0; nt < 2; ++nt){
    int colg = w * 32 + nt * 16 + lr;
    float bv = bias[colg];
    float cs = 0.f, cq = 0.f;
    #pragma unroll
    for (int mt = 0; mt < 2; ++mt){
      #pragma unroll
      for (int r = 0; r < 4; ++r){
        u16 yb = f2bf(acc[mt][nt][r] + bv);
        float yr = bf2f(yb);
        out[(row0 + mt * 16 + lk * 4 + r) * DD + colg] = yb;
        cs += yr; cq += yr * yr;
      }
    }
    atomicAdd(&s_sum[colg], cs);
    atomicAdd(&s_sq[colg], cq);
  }
  __syncthreads();
  float* slice = osum + (blockIdx.x & 7) * 256;
  if (tid < DD){
    atomicAdd(&slice[tid],      s_sum[tid]);
    atomicAdd(&slice[DD + tid], s_sq[tid]);
  }
}
#undef GG_LOAD
#undef GG_LOADA
#undef GG_CONS
#undef GG_DECLS
#undef GG_ISSUE
#undef GG_CONSUME
#undef GG_FIN
#undef GG_CLOSE

// ---------------- GEMM2: BN1+ReLU on input, MFMA @W2+b2, bf16 out + sliced stats2 ----------------
__global__ __launch_bounds__(256) void k_gemm2(const u16* __restrict__ Asrc,
    const u16* __restrict__ Wt, const float* __restrict__ bias,
    const float* __restrict__ stats_in,       // 8 slices x [sum128|sq128]
    const float* __restrict__ g, const float* __restrict__ bt,
    u16* __restrict__ out, float* __restrict__ osum){
  __shared__ u16 sA[32 * 136];
  __shared__ float s_scale[DD], s_shift[DD];
  __shared__ float s_sum[DD], s_sq[DD];
  int tid = threadIdx.x;
  int row0 = blockIdx.x * 32;
  if (tid < DD){
    s_sum[tid] = 0.f; s_sq[tid] = 0.f;
    float s = 0.f, q = 0.f;
    #pragma unroll
    for (int s8 = 0; s8 < 8; ++s8){
      s += stats_in[s8 * 256 + tid];
      q += stats_in[s8 * 256 + DD + tid];
    }
    float m   = s * (1.0f / NN);
    float var = q * (1.0f / NN) - m * m;
    float inv = rsqrtf(var + 1e-5f);
    float sc  = inv * g[tid];
    s_scale[tid] = sc;
    s_shift[tid] = bt[tid] - m * sc;
  }
  __syncthreads();
  #pragma unroll
  for (int c0 = 0; c0 < 2; ++c0){
    int c = tid + c0 * 256;
    int row = c >> 4, off = (c & 15) * 8;
    uint4 v = *(const uint4*)(Asrc + (row0 + row) * DD + off);
    u32 wv[4] = {v.x, v.y, v.z, v.w};
    union { u16 o[8]; uint4 v; } u;
    #pragma unroll
    for (int j = 0; j < 4; ++j){
      float y0 = bf2f(wv[j] & 0xFFFFu) * s_scale[off + 2*j]     + s_shift[off + 2*j];
      float y1 = bf2f(wv[j] >> 16)     * s_scale[off + 2*j + 1] + s_shift[off + 2*j + 1];
      u.o[2*j]     = f2bf(fmaxf(y0, 0.f));
      u.o[2*j + 1] = f2bf(fmaxf(y1, 0.f));
    }
    *(uint4*)(sA + row * 136 + off) = u.v;
  }
  int w = tid >> 6, lane = tid & 63, lr = lane & 15, lk = lane >> 4;
  bf8 bfr[2][4];
  #pragma unroll
  for (int nt = 0; nt < 2; ++nt){
    int n = w * 32 + nt * 16 + lr;
    #pragma unroll
    for (int kt = 0; kt < 4; ++kt)
      bfr[nt][kt] = *(const bf8*)(Wt + n * DD + kt * 32 + lk * 8);
  }
  __syncthreads();
  f4 acc[2][2];
  #pragma unroll
  for (int mt = 0; mt < 2; ++mt)
    #pragma unroll
    for (int nt = 0; nt < 2; ++nt) acc[mt][nt] = (f4){0.f, 0.f, 0.f, 0.f};
  #pragma unroll
  for (int kt = 0; kt < 4; ++kt){
    bf8 a0 = *(const bf8*)(sA + lr * 136        + kt * 32 + lk * 8);
    bf8 a1 = *(const bf8*)(sA + (16 + lr) * 136 + kt * 32 + lk * 8);
    acc[0][0] = __builtin_amdgcn_mfma_f32_16x16x32_bf16(a0, bfr[0][kt], acc[0][0], 0, 0, 0);
    acc[0][1] = __builtin_amdgcn_mfma_f32_16x16x32_bf16(a0, bfr[1][kt], acc[0][1], 0, 0, 0);
    acc[1][0] = __builtin_amdgcn_mfma_f32_16x16x32_bf16(a1, bfr[0][kt], acc[1][0], 0, 0, 0);
    acc[1][1] = __builtin_amdgcn_mfma_f32_16x16x32_bf16(a1, bfr[1][kt], acc[1][1], 0, 0, 0);
  }
  #pragma unroll
  for (int nt = 0; nt < 2; ++nt){
    int colg = w * 32 + nt * 16 + lr;
    float bv = bias[colg];
    float cs = 0.f, cq = 0.f;
    #pragma unroll
    for (int mt = 0; mt < 2; ++mt){
      #pragma unroll
      for (int r = 0; r < 4; ++r){
        u16 yb = f2bf(acc[mt][nt][r] + bv);
        float yr = bf2f(yb);
        out[(row0 + mt * 16 + lk * 4 + r) * DD + colg] = yb;
        cs += yr; cq += yr * yr;
      }
    }
    atomicAdd(&s_sum[colg], cs);
    atomicAdd(&s_sq[colg], cq);
  }
  __syncthreads();
  float* slice = osum + (blockIdx.x & 7) * 256;
  if (tid < DD){
    atomicAdd(&slice[tid],      s_sum[tid]);
    atomicAdd(&slice[DD + tid], s_sq[tid]);
  }
}

// ---------------- BN2 (+ReLU except last) + residual; 4 feats/thread; block 0 zeroes stats1 ----------------
// do_relu gates both the ReLU and the hb mirror write (hb is dead after the last layer).
__global__ void k_final(const u32* __restrict__ zf, const float* __restrict__ stats2,
                        const float* __restrict__ gl, const float* __restrict__ bl,
                        float* __restrict__ h, u32* __restrict__ hb, int do_relu,
                        float* __restrict__ stats1){
  __shared__ float s_scale[DD], s_shift[DD];
  int tid = threadIdx.x;
  if (blockIdx.x == 0){                           // zero stats1 for next layer's k_gg
    #pragma unroll
    for (int j = 0; j < 8; ++j) stats1[j * 256 + tid] = 0.f;
  }
  if (tid < DD){
    float s = 0.f, q = 0.f;
    #pragma unroll
    for (int s8 = 0; s8 < 8; ++s8){
      s += stats2[s8 * 256 + tid];
      q += stats2[s8 * 256 + DD + tid];
    }
    float m   = s * (1.0f / NN);
    float var = q * (1.0f / NN) - m * m;
    float inv = rsqrtf(var + 1e-5f);
    float sc  = inv * gl[tid];
    s_scale[tid] = sc;
    s_shift[tid] = bl[tid] - m * sc;
  }
  __syncthreads();
  int idx = blockIdx.x * 256 + tid;           // NN*32 items, 4 feats each
  int j0 = (idx & 31) * 4;
  uint2 zz = ((const uint2*)zf)[idx];
  float val0 = bf2f(zz.x & 0xFFFFu) * s_scale[j0]     + s_shift[j0];
  float val1 = bf2f(zz.x >> 16)     * s_scale[j0 + 1] + s_shift[j0 + 1];
  float val2 = bf2f(zz.y & 0xFFFFu) * s_scale[j0 + 2] + s_shift[j0 + 2];
  float val3 = bf2f(zz.y >> 16)     * s_scale[j0 + 3] + s_shift[j0 + 3];
  if (do_relu){
    val0 = fmaxf(val0, 0.f); val1 = fmaxf(val1, 0.f);
    val2 = fmaxf(val2, 0.f); val3 = fmaxf(val3, 0.f);
  }
  float4 hv = ((float4*)h)[idx];
  hv.x += val0; hv.y += val1; hv.z += val2; hv.w += val3;
  ((float4*)h)[idx] = hv;
  if (do_relu){                                   // last layer: hb is dead, skip the write
    uint2 hp; hp.x = pack2(hv.x, hv.y); hp.y = pack2(hv.z, hv.w);
    ((uint2*)hb)[idx] = hp;
  }
}

extern "C" void kernel_launch(void* const* d_in, const int* in_sizes, int n_in,
                              void* d_out, int out_size, void* d_ws, size_t ws_size,
                              hipStream_t stream) {
  const int*   x_ids      = (const int*)d_in[0];
  const int*   edge_index = (const int*)d_in[1];
  const int*   edge_attr  = (const int*)d_in[2];
  const float* atom_emb   = (const float*)d_in[3];
  const float* bond_emb   = (const float*)d_in[4];
  const float* W1    = (const float*)d_in[5];
  const float* b1    = (const float*)d_in[6];
  const float* g1    = (const float*)d_in[7];
  const float* bt1   = (const float*)d_in[8];
  const float* W2    = (const float*)d_in[9];
  const float* b2    = (const float*)d_in[10];
  const float* eps   = (const float*)d_in[11];
  const float* g_out = (const float*)d_in[12];
  const float* b_out = (const float*)d_in[13];

  float* h   = (float*)d_out;                 // NN*DD fp32 running node state
  u32*   zb  = (u32*)d_ws;                    // prologue: bin store; loop: unused
  u32*   z2b = zb  + NN * 64;                 // NN*64: bf16 gemm1 out
  u32*   zAb = z2b + NN * 64;                 // NN*64: bf16 gemm2 out
  u32*   hb  = zAb + NN * 64;                 // (NN+1)*64: bf16 mirror of h + sentinel row
  u16*   wt  = (u16*)(hb + (NN + 1) * 64);    // 10*16384 bf16 transposed weights
  float* stats = (float*)(wt + 10 * 16384);   // 4096: stats1[0..2047] | stats2[2048..4095]
  int* rs        = (int*)(stats + 4096);      // NN+4 (chunk-local scan)
  int* rs2       = rs + NN + 4;               // NN+4 (finalized row offsets)
  int* deg       = rs2 + NN + 4;
  int* col       = deg + NN;                  // EE + 7*NN (x8-padded)
  int* bsum      = col + EE + 7 * NN;         // 40
  int* gcur      = bsum + 64;                 // 160 bucket cursors

  u32* store = zb;                            // NB*CAP u32 records (5.1 MB; dead before loop)

  k_pre   <<<5640, 256, 0, stream>>>(x_ids, atom_emb, h, hb, deg, W1, W2, wt, gcur);
  k_bin   <<<NB, 1024, 0, stream>>>(edge_index, edge_attr, deg, gcur, store);
  k_scan1 <<<40, 1024, 0, stream>>>(deg, rs, bsum);
  k_place2<<<NB, 1024, 0, stream>>>(store, gcur, rs, rs2, col, bsum, stats, x_ids);

  for (int l = 0; l < LL; ++l){
    if (l == 0)
      k_gg<true> <<<NN / 32, 256, 0, stream>>>(h, hb, rs2, col,
                                               bond_emb + l * 4 * DD, eps + l,
                                               wt + l * 16384, b1 + l * DD,
                                               (u16*)z2b, stats, stats + 2048, atom_emb);
    else
      k_gg<false><<<NN / 32, 256, 0, stream>>>(h, hb, rs2, col,
                                               bond_emb + l * 4 * DD, eps + l,
                                               wt + l * 16384, b1 + l * DD,
                                               (u16*)z2b, stats, stats + 2048, atom_emb);
    k_gemm2<<<NN / 32, 256, 0, stream>>>((const u16*)z2b, wt + (LL + l) * 16384, b2 + l * DD,
                                         stats, g1 + l * DD, bt1 + l * DD,
                                         (u16*)zAb, stats + 2048);
    k_final<<<NN * 32 / 256, 256, 0, stream>>>(zAb, stats + 2048,
                                               g_out + l * DD, b_out + l * DD,
                                               h, hb, (l < LL - 1) ? 1 : 0, stats);
  }
}